// Round 10
// baseline (1275.267 us; speedup 1.0000x reference)
//
#include <hip/hip_runtime.h>
#include <hip/hip_bf16.h>
#include <math.h>

// Sizes fixed by the problem
#define BB 32
#define TT 128
#define KK 256
#define HH 512
#define VV 10000
#define VP 10240
#define BT 4096           // B*T
#define HLOG2PI 0.91893853320467274178f

// ---- workspace layout (float offsets) ----
// z       : 0          1048576   (BT*K, f32 — used by k_xp / k_gx)
// qz      : 1048576    4096
// hb      : 1052672    1048576 floats worth = BT*H bf16 (ushort)
// zb      : 2101248    524288 floats worth  = BT*K bf16 (ushort)
// gx      : 3149824    4096
// region  : 3252224    13117440
//  phase 1 (lstm): xp / wpIF / wpGO / hpk  (see offsets below)
//  phase 2 (scores), overlaying dead xp: Pb / Qb / Gb / part / cv

typedef short bf16x8 __attribute__((ext_vector_type(8)));
typedef float f32x4 __attribute__((ext_vector_type(4)));

__device__ __forceinline__ float softplus_b(float x) {
    float ax = fabsf(x);
    return fmaxf(x, 0.0f) + log2f(1.0f + exp2f(-ax));
}
__device__ __forceinline__ float sigm(float x) { return 1.0f / (1.0f + expf(-x)); }
// fast variants for the LSTM serial gate path (bf16-level accuracy is plenty)
__device__ __forceinline__ float fsigm(float x) { return 1.0f / (1.0f + __expf(-x)); }
__device__ __forceinline__ float ftanh(float x) {
    float e = __expf(2.0f * x);
    return 1.0f - 2.0f / (e + 1.0f);
}
__device__ __forceinline__ unsigned short f2bf(float f) {
    unsigned u = __float_as_uint(f);
    u += 0x7FFFu + ((u >> 16) & 1u);
    return (unsigned short)(u >> 16);
}
typedef _Float16 h2f16 __attribute__((ext_vector_type(2)));
__device__ __forceinline__ unsigned pkh2(float a, float b) {
    h2f16 h;
    h.x = (_Float16)a;
    h.y = (_Float16)b;
    return *(unsigned*)&h;
}
__device__ __forceinline__ float fdot2u(unsigned a, unsigned b, float c) {
    h2f16 ah = *(h2f16*)&a, bh = *(h2f16*)&b;
#if __has_builtin(__builtin_amdgcn_fdot2)
    return __builtin_amdgcn_fdot2(ah, bh, c, false);
#else
    return c + (float)ah.x * (float)bh.x + (float)ah.y * (float)bh.y;
#endif
}
// square a bf16x8 in-register: bf16->f32 is <<16; repack with v_cvt_pk_bf16_f32 (RNE)
__device__ __forceinline__ bf16x8 bsq(bf16x8 a) {
    union { bf16x8 v; unsigned w[4]; } u, r;
    u.v = a;
#pragma unroll
    for (int i = 0; i < 4; i++) {
        float lo = __uint_as_float(u.w[i] << 16);
        float hi = __uint_as_float(u.w[i] & 0xFFFF0000u);
        lo *= lo;
        hi *= hi;
        asm("v_cvt_pk_bf16_f32 %0, %1, %2" : "=v"(r.w[i]) : "v"(lo), "v"(hi));
    }
    return r.v;
}

// ---------------- 1) embedding -> z (f32 + bf16), q_z_lp ----------------
__global__ void k_embed(const int* __restrict__ x, const int* __restrict__ x_sl,
                        const float* __restrict__ eps, const float* __restrict__ emb,
                        float* __restrict__ z, ushort* __restrict__ zb,
                        float* __restrict__ qz) {
    int bt = blockIdx.x;
    int b = bt >> 7, t = bt & 127;
    int k = threadIdx.x;
    int xi = x[bt];
    float e1 = emb[xi * 512 + k];
    float sg = softplus_b(emb[xi * 512 + 256 + k]);
    float ep = eps[bt * 256 + k];
    float mk = (t < x_sl[b]) ? 1.f : 0.f;
    float zv = (e1 + sg * ep) * mk;
    z[bt * 256 + k] = zv;
    zb[bt * 256 + k] = f2bf(zv);
    float q = -HLOG2PI - logf(sg) - 0.5f * ep * ep;
    __shared__ float red[256];
    red[k] = q;
    __syncthreads();
    for (int s = 128; s > 0; s >>= 1) {
        if (k < s) red[k] += red[k + s];
        __syncthreads();
    }
    if (k == 0) qz[bt] = red[0];
}

// ---------------- 2) x_proj = z_shift @ w_ih^T + b_ih + b_hh ----------------
__global__ __launch_bounds__(256) void k_xp(const float* __restrict__ z,
                                            const float* __restrict__ w_ih,
                                            const float* __restrict__ b_ih,
                                            const float* __restrict__ b_hh,
                                            float* __restrict__ xp) {
    __shared__ float At[64][68];
    __shared__ float Wt[64][68];
    int n0 = blockIdx.x * 64, m0 = blockIdx.y * 64;
    int tid = threadIdx.x;
    int tn = tid & 15, tm = tid >> 4;
    float acc[4][4] = {};
    for (int kc = 0; kc < 256; kc += 64) {
        __syncthreads();
        for (int i = tid; i < 1024; i += 256) {
            int r = i >> 4, c4 = i & 15;
            int bt = m0 + r;
            int t = bt & 127;
            float4 v = make_float4(0.f, 0.f, 0.f, 0.f);
            if (t > 0) v = *(const float4*)(z + (bt - 1) * 256 + kc + c4 * 4);
            *(float4*)&At[r][c4 * 4] = v;
        }
        for (int i = tid; i < 1024; i += 256) {
            int r = i >> 4, c4 = i & 15;
            float4 v = *(const float4*)(w_ih + (n0 + r) * 256 + kc + c4 * 4);
            *(float4*)&Wt[r][c4 * 4] = v;
        }
        __syncthreads();
        for (int kk = 0; kk < 16; kk++) {
            float4 a[4], w[4];
#pragma unroll
            for (int i = 0; i < 4; i++) a[i] = *(const float4*)&At[tm + 16 * i][kk * 4];
#pragma unroll
            for (int j = 0; j < 4; j++) w[j] = *(const float4*)&Wt[tn + 16 * j][kk * 4];
#pragma unroll
            for (int i = 0; i < 4; i++)
#pragma unroll
                for (int j = 0; j < 4; j++)
                    acc[i][j] += a[i].x * w[j].x + a[i].y * w[j].y + a[i].z * w[j].z + a[i].w * w[j].w;
        }
    }
#pragma unroll
    for (int i = 0; i < 4; i++) {
        int m = m0 + tm + 16 * i;
#pragma unroll
        for (int j = 0; j < 4; j++) {
            int n = n0 + tn + 16 * j;
            xp[m * 2048 + n] = acc[i][j] + b_ih[n] + b_hh[n];
        }
    }
}

// ---------------- 2b) pack w_hh -> f16 pairs, layouts for k_lstm v2 ----------------
__global__ __launch_bounds__(256) void k_wpack2(const float* __restrict__ w_hh,
                                                uint4* __restrict__ wpIF,
                                                uint4* __restrict__ wpGO) {
    int o = blockIdx.x * 256 + threadIdx.x;  // 0..65535
    if (blockIdx.y == 0) {
        int kq = o & 3, j_local = (o >> 2) & 63, q = (o >> 8) & 31, m = o >> 13;
        int jg = (m << 6) + j_local;
        int k = (kq << 7) + (q << 2);
        const float* wi = w_hh + (size_t)jg * 512 + k;
        const float* wf = w_hh + (size_t)(512 + jg) * 512 + k;
        uint4 u;
        u.x = pkh2(wi[0], wi[1]); u.y = pkh2(wi[2], wi[3]);
        u.z = pkh2(wf[0], wf[1]); u.w = pkh2(wf[2], wf[3]);
        wpIF[o] = u;
    } else {
        int q = o & 31, kq = (o >> 5) & 3, j_local = (o >> 7) & 63, m = o >> 13;
        int jg = (m << 6) + j_local;
        int k = (kq << 7) + (q << 2);
        const float* wg = w_hh + (size_t)(1024 + jg) * 512 + k;
        const float* wo = w_hh + (size_t)(1536 + jg) * 512 + k;
        uint4 u;
        u.x = pkh2(wg[0], wg[1]); u.y = pkh2(wg[2], wg[3]);
        u.z = pkh2(wo[0], wo[1]); u.w = pkh2(wo[2], wo[3]);
        wpGO[o] = u;
    }
}

// ---------------- 3) LSTM v4: skewed h-exchange, agent-scope poll ----------------
// v3 (r9) post-mortem: skew fix verified (SQ_LDS_BANK_CONFLICT 5e7 -> 0) but
// the volatile "L2 fast-poll" compiled to cache-bypassing loads — every spin
// hit HBM (FETCH 27 MB -> 555 MB, dur 348 -> 740). v4 keeps the skewed
// conflict-free exchange + fast transcendentals, reverts the poll to the
// original agent-scope atomic load (27 MB FETCH, cache-served).
__global__ __launch_bounds__(256, 1) void k_lstm(const float* __restrict__ xp,
                                                 const uint4* __restrict__ wpIF,
                                                 const uint4* __restrict__ wpGO,
                                                 ushort* __restrict__ h_all,
                                                 unsigned* __restrict__ hpk) {
    extern __shared__ char smc[];
    uint4* wif = (uint4*)smc;                   // [q 32][wave-linear 256] = 128 KB
    unsigned* hs2 = (unsigned*)(smc + 131072);  // [2][272] dwords (skewed)
    int bid = blockIdx.x;
    int b = bid & 31;
    int m = bid >> 5;
    int tid = threadIdx.x;
    int w = tid >> 6, l = tid & 63;
    int jj = l >> 2, kq = l & 3;
    int j_local = (w << 4) + jj;
    int j_global = (m << 6) + j_local;
    const uint4* srcIF = wpIF + ((size_t)m << 13);
    for (int i = tid; i < 8192; i += 256) wif[i] = srcIF[i];
    uint4 wgo[32];
    const uint4* srcGO = wpGO + ((size_t)((((m << 6) + j_local) << 2) + kq) << 5);
#pragma unroll
    for (int q = 0; q < 32; q++) wgo[q] = srcGO[q];
    const uint4* wifp = wif + (w << 6) + l;
    int skslot = tid + ((tid >> 6) << 2);  // skewed write slot
    float c = 0.f;
    __syncthreads();
    for (int t = 0; t < 128; t++) {
        int bt = (b << 7) + t;
        float xg0 = 0.f, xg1 = 0.f, xg2 = 0.f, xg3 = 0.f;
        if (kq == 0) {  // prefetch xp before the poll (independent loads)
            const float* xpr = xp + (size_t)bt * 2048 + j_global;
            xg0 = xpr[0]; xg1 = xpr[512]; xg2 = xpr[1024]; xg3 = xpr[1536];
        }
        float a0 = 0.f, a1 = 0.f, a2 = 0.f, a3 = 0.f;
        if (t > 0) {
            const unsigned* src = hpk + ((size_t)(bt - 1) << 8);
            unsigned u;
            do {
                u = __hip_atomic_load(src + tid, __ATOMIC_RELAXED, __HIP_MEMORY_SCOPE_AGENT);
            } while (u == 0xFFFFFFFFu);
            unsigned* hbuf = hs2 + ((t - 1) & 1) * 272;
            hbuf[skslot] = u;
            __syncthreads();
            const uint4* hp4 = (const uint4*)(hbuf + kq * 68);
#pragma unroll 4
            for (int qq = 0; qq < 16; qq++) {
                uint4 H = hp4[qq];  // broadcast within jj-group; banks disjoint by kq
                uint4 A = wifp[(qq * 2) << 8];
                uint4 B = wgo[qq * 2];
                a0 = fdot2u(A.x, H.x, a0); a0 = fdot2u(A.y, H.y, a0);
                a1 = fdot2u(A.z, H.x, a1); a1 = fdot2u(A.w, H.y, a1);
                a2 = fdot2u(B.x, H.x, a2); a2 = fdot2u(B.y, H.y, a2);
                a3 = fdot2u(B.z, H.x, a3); a3 = fdot2u(B.w, H.y, a3);
                A = wifp[(qq * 2 + 1) << 8];
                B = wgo[qq * 2 + 1];
                a0 = fdot2u(A.x, H.z, a0); a0 = fdot2u(A.y, H.w, a0);
                a1 = fdot2u(A.z, H.z, a1); a1 = fdot2u(A.w, H.w, a1);
                a2 = fdot2u(B.x, H.z, a2); a2 = fdot2u(B.y, H.w, a2);
                a3 = fdot2u(B.z, H.z, a3); a3 = fdot2u(B.w, H.w, a3);
            }
#pragma unroll
            for (int off = 1; off <= 2; off <<= 1) {
                a0 += __shfl_xor(a0, off);
                a1 += __shfl_xor(a1, off);
                a2 += __shfl_xor(a2, off);
                a3 += __shfl_xor(a3, off);
            }
        }
        float h = 0.f;
        if (kq == 0) {
            float g0 = xg0 + a0, g1 = xg1 + a1, g2 = xg2 + a2, g3 = xg3 + a3;
            c = fsigm(g1) * c + fsigm(g0) * ftanh(g2);
            h = fsigm(g3) * ftanh(c);
            h_all[(size_t)bt * 512 + j_global] = f2bf(h);  // bf16, read post-kernel
        }
        float hp = __shfl_xor(h, 4);  // leader jj even <- h of jj+1
        if (kq == 0 && (jj & 1) == 0) {
            unsigned u = pkh2(h, hp);
            __hip_atomic_store(hpk + ((size_t)bt << 8) + (m << 5) + (w << 3) + (jj >> 1),
                               u, __ATOMIC_RELAXED, __HIP_MEMORY_SCOPE_AGENT);
        }
    }
}

// ---------------- 4a) cast weights -> bf16 row-major [v][K], pad rows zeroed ----------------
__global__ __launch_bounds__(256) void k_pack_w(const float* __restrict__ src,
                                                ushort* __restrict__ dst, int kshift) {
    int o = blockIdx.x * 256 + threadIdx.x;  // one ushort4 unit
    int c = o & ((1 << kshift) - 1);
    int r = o >> kshift;
    ushort4 u = make_ushort4(0, 0, 0, 0);
    if (r < VV) {
        float4 v = *(const float4*)(src + ((size_t)r << (kshift + 2)) + (c << 2));
        u = make_ushort4(f2bf(v.x), f2bf(v.y), f2bf(v.z), f2bf(v.w));
    }
    *(ushort4*)(dst + ((size_t)o << 2)) = u;
}

// ---------------- 4b) Qb rows [2*iv*mu (256) | -iv (256)] bf16 + const_v ----------------
__global__ void k_pack_q(const float* __restrict__ emb, ushort* __restrict__ Qb,
                         float* __restrict__ cv) {
    int v = blockIdx.x, k = threadIdx.x;
    if (v >= VV) {
        Qb[((size_t)v << 9) + k] = 0;
        Qb[((size_t)v << 9) + 256 + k] = 0;
        if (k == 0) cv[v] = 0.f;
        return;
    }
    float mu = emb[(size_t)v * 512 + k];
    float sg = softplus_b(emb[(size_t)v * 512 + 256 + k]);
    float iv = 0.5f / (sg * sg);
    Qb[((size_t)v << 9) + k] = f2bf(2.f * iv * mu);
    Qb[((size_t)v << 9) + 256 + k] = f2bf(-iv);
    float ct = -HLOG2PI - logf(sg) - mu * mu * iv;
    __shared__ float red[256];
    red[k] = ct;
    __syncthreads();
    for (int s = 128; s > 0; s >>= 1) {
        if (k < s) red[k] += red[k + s];
        __syncthreads();
    }
    if (k == 0) cv[v] = red[0];
}

// ---------------- 6) fused scores v6: ms=4 retile (B-reuse 2->4) ----------------
__global__ __launch_bounds__(512, 2) void k_scores(
    const ushort* __restrict__ hb, const ushort* __restrict__ zb,
    const ushort* __restrict__ Pb, const ushort* __restrict__ Qb,
    const ushort* __restrict__ Gb, const float* __restrict__ cv,
    const float* __restrict__ b_prior, const float* __restrict__ b_gen,
    float* __restrict__ part) {
    extern __shared__ ushort sm[];
    ushort* hT = sm;           // [kc 16][64 rows][32], swizzled granules = 64 KB
    ushort* fzT = sm + 32768;  // [kc 16][64 rows][32]: kc<8 z, kc>=8 z^2 = 64 KB
    int tid = threadIdx.x;
    int vs = blockIdx.x & 7;
    int mb = blockIdx.x >> 3;
    int bt0 = mb << 6;
    int vbase = vs * 1280;
    // stage h tile (64 x 512 bf16): pure 16B copies
    for (int i = tid; i < 4096; i += 512) {
        int quad = i & 3, row = (i >> 2) & 63, kc = i >> 8;
        uint4 v = *(const uint4*)(hb + (size_t)(bt0 + row) * 512 + kc * 32 + quad * 8);
        int g = (((row << 2) + (quad ^ (row & 3))) ^ (((row >> 2) & 1) << 2));
        *(uint4*)(hT + kc * 2048 + g * 8) = v;
    }
    // stage z (copy) + z^2 (bsq once per granule)
    for (int i = tid; i < 2048; i += 512) {
        int quad = i & 3, row = (i >> 2) & 63, kc = i >> 8;  // kc 0..7
        uint4 v = *(const uint4*)(zb + (size_t)(bt0 + row) * 256 + kc * 32 + quad * 8);
        int g = (((row << 2) + (quad ^ (row & 3))) ^ (((row >> 2) & 1) << 2));
        *(uint4*)(fzT + kc * 2048 + g * 8) = v;
        bf16x8 sq = bsq(*(bf16x8*)&v);
        *(uint4*)(fzT + (kc + 8) * 2048 + g * 8) = *(uint4*)&sq;
    }
    __syncthreads();
    int w = tid >> 6, l = tid & 63;
    int quad = l >> 4, ln = l & 15;
    int nq = w;  // wave: ALL 64 rows x cols nq*32..+32 per nt group
    const bf16x8* hT8 = (const bf16x8*)hT;
    const bf16x8* fz8 = (const bf16x8*)fzT;
    const bf16x8* Pb8 = (const bf16x8*)Pb;
    const bf16x8* Qb8 = (const bf16x8*)Qb;
    const bf16x8* Gb8 = (const bf16x8*)Gb;
    // ms=0 row = ln; ms adds 16 rows => granule g0 + 64*ms (swizzle-consistent)
    int g0 = (((ln << 2) + (quad ^ (ln & 3))) ^ (((ln >> 2) & 1) << 2));
    float Lm[3][16], Ls[3][16];
#pragma unroll
    for (int c = 0; c < 3; c++)
#pragma unroll
        for (int r = 0; r < 16; r++) { Lm[c][r] = -1e30f; Ls[c][r] = 0.f; }
#pragma unroll 1
    for (int nt = 0; nt < 5; nt++) {
        int n0 = vbase + (nt << 8) + (nq << 5);
        int rb = (n0 + ln) << 6;  // Pb/Qb granule row base (ns adds 1024)
        int rg = (n0 + ln) << 5;  // Gb granule row base (ns adds 512)
        __builtin_amdgcn_s_setprio(1);
        // ---- chain A: prior logits, h (K=512) vs Pb ----
        f32x4 accA[4][2];
#pragma unroll
        for (int ms = 0; ms < 4; ms++) { accA[ms][0] = 0.f; accA[ms][1] = 0.f; }
#pragma unroll 2
        for (int kc = 0; kc < 16; kc++) {
            bf16x8 b0 = Pb8[rb + (kc << 2) + quad];
            bf16x8 b1 = Pb8[rb + 1024 + (kc << 2) + quad];
#pragma unroll
            for (int ms = 0; ms < 4; ms++) {
                bf16x8 a = hT8[(kc << 8) + g0 + (ms << 6)];
                accA[ms][0] = __builtin_amdgcn_mfma_f32_16x16x32_bf16(a, b0, accA[ms][0], 0, 0, 0);
                accA[ms][1] = __builtin_amdgcn_mfma_f32_16x16x32_bf16(a, b1, accA[ms][1], 0, 0, 0);
            }
        }
        __builtin_amdgcn_s_setprio(0);
        // ---- epilogue A: LSE0; fold u1+cv into accB init ----
        f32x4 accB[4][2];
#pragma unroll
        for (int ns = 0; ns < 2; ns++) {
            int col = n0 + (ns << 4) + ln;
            bool ok = col < VV;
            float bpv = ok ? b_prior[col] : 0.f;
            float cvv = ok ? cv[col] : 0.f;
#pragma unroll
            for (int ms = 0; ms < 4; ms++)
#pragma unroll
                for (int r = 0; r < 4; r++) {
                    int r16 = (ms << 2) + r;
                    float u1 = ok ? accA[ms][ns][r] + bpv : -1e30f;
                    float nm = fmaxf(Lm[0][r16], u1);
                    Ls[0][r16] = Ls[0][r16] * __expf(Lm[0][r16] - nm) + __expf(u1 - nm);
                    Lm[0][r16] = nm;
                    accB[ms][ns][r] = ok ? u1 + cvv : -1e30f;  // pad Qb rows are 0
                }
        }
        __builtin_amdgcn_s_setprio(1);
        // ---- chain B: z (kc 0..7) + z^2 (kc 8..15) vs Qb ----
#pragma unroll 2
        for (int kc = 0; kc < 16; kc++) {
            bf16x8 bq0 = Qb8[rb + (kc << 2) + quad];
            bf16x8 bq1 = Qb8[rb + 1024 + (kc << 2) + quad];
#pragma unroll
            for (int ms = 0; ms < 4; ms++) {
                bf16x8 a = fz8[(kc << 8) + g0 + (ms << 6)];
                accB[ms][0] = __builtin_amdgcn_mfma_f32_16x16x32_bf16(a, bq0, accB[ms][0], 0, 0, 0);
                accB[ms][1] = __builtin_amdgcn_mfma_f32_16x16x32_bf16(a, bq1, accB[ms][1], 0, 0, 0);
            }
        }
        __builtin_amdgcn_s_setprio(0);
        // ---- epilogue B: LSE1 ----
#pragma unroll
        for (int ns = 0; ns < 2; ns++)
#pragma unroll
            for (int ms = 0; ms < 4; ms++)
#pragma unroll
                for (int r = 0; r < 4; r++) {
                    int r16 = (ms << 2) + r;
                    float u2 = accB[ms][ns][r];
                    float nm = fmaxf(Lm[1][r16], u2);
                    Ls[1][r16] = Ls[1][r16] * __expf(Lm[1][r16] - nm) + __expf(u2 - nm);
                    Lm[1][r16] = nm;
                }
        // ---- chain C: gen logits, z (K=256) vs Gb ----
        f32x4 accC[4][2];
#pragma unroll
        for (int ns = 0; ns < 2; ns++) {
            int col = n0 + (ns << 4) + ln;
            bool ok = col < VV;
            float bgv = ok ? b_gen[col] : -1e30f;  // pad Gb rows are 0
#pragma unroll
            for (int ms = 0; ms < 4; ms++) accC[ms][ns] = bgv;
        }
        __builtin_amdgcn_s_setprio(1);
#pragma unroll 2
        for (int kc = 0; kc < 8; kc++) {
            bf16x8 bg0 = Gb8[rg + (kc << 2) + quad];
            bf16x8 bg1 = Gb8[rg + 512 + (kc << 2) + quad];
#pragma unroll
            for (int ms = 0; ms < 4; ms++) {
                bf16x8 a = fz8[(kc << 8) + g0 + (ms << 6)];
                accC[ms][0] = __builtin_amdgcn_mfma_f32_16x16x32_bf16(a, bg0, accC[ms][0], 0, 0, 0);
                accC[ms][1] = __builtin_amdgcn_mfma_f32_16x16x32_bf16(a, bg1, accC[ms][1], 0, 0, 0);
            }
        }
        __builtin_amdgcn_s_setprio(0);
        // ---- epilogue C: LSE2 ----
#pragma unroll
        for (int ns = 0; ns < 2; ns++)
#pragma unroll
            for (int ms = 0; ms < 4; ms++)
#pragma unroll
                for (int r = 0; r < 4; r++) {
                    int r16 = (ms << 2) + r;
                    float u3 = accC[ms][ns][r];
                    float nm = fmaxf(Lm[2][r16], u3);
                    Ls[2][r16] = Ls[2][r16] * __expf(Lm[2][r16] - nm) + __expf(u3 - nm);
                    Lm[2][r16] = nm;
                }
    }
    // merge across the 16 col-lanes (same rows; xor of low-4 bits keeps quad)
#pragma unroll
    for (int off = 1; off <= 8; off <<= 1)
#pragma unroll
        for (int c = 0; c < 3; c++)
#pragma unroll
            for (int r16 = 0; r16 < 16; r16++) {
                float mo = __shfl_xor(Lm[c][r16], off);
                float so = __shfl_xor(Ls[c][r16], off);
                float nm = fmaxf(Lm[c][r16], mo);
                Ls[c][r16] = Ls[c][r16] * __expf(Lm[c][r16] - nm) + so * __expf(mo - nm);
                Lm[c][r16] = nm;
            }
    // block-level merge across the 8 wave column-slices (staging LDS dead now)
    __syncthreads();
    float* bm = (float*)sm;  // [3][8 w][64 rows]
    float* bs = bm + 1536;
    if (ln == 0) {
#pragma unroll
        for (int c = 0; c < 3; c++)
#pragma unroll
            for (int r16 = 0; r16 < 16; r16++) {
                int row = ((r16 >> 2) << 4) + (quad << 2) + (r16 & 3);
                bm[(c * 8 + w) * 64 + row] = Lm[c][r16];
                bs[(c * 8 + w) * 64 + row] = Ls[c][r16];
            }
    }
    __syncthreads();
    if (tid < 192) {
        int c = tid >> 6, row = tid & 63;
        float M = -1e30f, S = 0.f;
#pragma unroll
        for (int q = 0; q < 8; q++) {
            float m = bm[(c * 8 + q) * 64 + row];
            float s = bs[(c * 8 + q) * 64 + row];
            float Mn = fmaxf(M, m);
            S = S * __expf(M - Mn) + s * __expf(m - Mn);
            M = Mn;
        }
        part[(vs * 6 + c * 2) * 4096 + bt0 + row] = M;
        part[(vs * 6 + c * 2 + 1) * 4096 + bt0 + row] = S;
    }
}

// ---------------- 7) gx = z . w_gen[x] + b_gen[x] ----------------
__global__ void k_gx(const float* __restrict__ z, const int* __restrict__ x,
                     const float* __restrict__ w_gen, const float* __restrict__ b_gen,
                     float* __restrict__ gx) {
    int bt = blockIdx.x, k = threadIdx.x;
    int xi = x[bt];
    float p = z[bt * 256 + k] * w_gen[xi * 256 + k];
    __shared__ float red[256];
    red[k] = p;
    __syncthreads();
    for (int s = 128; s > 0; s >>= 1) {
        if (k < s) red[k] += red[k + s];
        __syncthreads();
    }
    if (k == 0) gx[bt] = red[0] + b_gen[xi];
}

// ---------------- 8) finalize (merge 8 V-split partials) ----------------
__device__ __forceinline__ float lse8(const float* __restrict__ part, int comp, int bt) {
    float M = -1e30f, S = 0.f;
#pragma unroll
    for (int vsi = 0; vsi < 8; vsi++) {
        float m = part[(vsi * 6 + comp) * 4096 + bt];
        float s = part[(vsi * 6 + comp + 1) * 4096 + bt];
        float Mn = fmaxf(M, m);
        S = S * __expf(M - Mn) + s * __expf(m - Mn);
        M = Mn;
    }
    return M + logf(S);
}

__global__ void k_final(const float* __restrict__ part, const float* __restrict__ qz,
                        const float* __restrict__ gxv, const int* __restrict__ x_sl,
                        float* __restrict__ out) {
    int tid = threadIdx.x;
    float S = 0.f;
    for (int bt = tid; bt < 4096; bt += 256) {
        int b = bt >> 7, t = bt & 127;
        if (t < x_sl[b]) {
            float lse1 = lse8(part, 0, bt);
            float lse2 = lse8(part, 2, bt);
            float lse3 = lse8(part, 4, bt);
            float p_z = lse2 - lse1;
            float kl = qz[bt] - p_z;
            float px = gxv[bt] - lse3;
            S += px - kl;
        }
    }
    __shared__ float red[256];
    red[tid] = S;
    __syncthreads();
    for (int s = 128; s > 0; s >>= 1) {
        if (tid < s) red[tid] += red[tid + s];
        __syncthreads();
    }
    if (tid == 0) {
        int sl = 0;
        for (int b = 0; b < 32; b++) sl += x_sl[b];
        out[0] = -(red[0] / (float)sl);
    }
}

extern "C" void kernel_launch(void* const* d_in, const int* in_sizes, int n_in,
                              void* d_out, int out_size, void* d_ws, size_t ws_size,
                              hipStream_t stream) {
    const int* x = (const int*)d_in[0];
    const int* x_sl = (const int*)d_in[1];
    const float* eps = (const float*)d_in[2];
    const float* emb = (const float*)d_in[3];
    const float* w_ih = (const float*)d_in[4];
    const float* w_hh = (const float*)d_in[5];
    const float* b_ih = (const float*)d_in[6];
    const float* b_hh = (const float*)d_in[7];
    const float* w_prior = (const float*)d_in[8];
    const float* b_prior = (const float*)d_in[9];
    const float* w_gen = (const float*)d_in[10];
    const float* b_gen = (const float*)d_in[11];

    float* ws = (float*)d_ws;
    float* z = ws;
    float* qz = ws + 1048576;
    ushort* hb = (ushort*)(ws + 1052672);            // BT*H bf16 = 4 MB
    ushort* zb = (ushort*)(ws + 1052672 + 1048576);  // BT*K bf16 = 2 MB
    float* gx = ws + 3149824;
    float* region = ws + 3252224;
    float* xp = region;
    uint4* wpIF = (uint4*)(region + 8388608);
    uint4* wpGO = wpIF + 65536;
    unsigned* hpk = (unsigned*)(region + 8912896);  // 1048576 dwords
    ushort* Pb = (ushort*)(region);                 // phase 2 (xp dead)
    ushort* Qb = (ushort*)(region + 2621440);
    ushort* Gb = (ushort*)(region + 5242880);
    float* part = region + 6553600;                 // 8*6*4096
    float* cv = region + 13107200;

    k_embed<<<4096, 256, 0, stream>>>(x, x_sl, eps, emb, z, zb, qz);
    k_xp<<<dim3(32, 64), 256, 0, stream>>>(z, w_ih, b_ih, b_hh, xp);
    k_wpack2<<<dim3(256, 2), 256, 0, stream>>>(w_hh, wpIF, wpGO);
    hipMemsetAsync(hpk, 0xFF, 4194304, stream);  // sentinel: f16 NaN pairs
    {
        hipFuncSetAttribute((const void*)k_lstm, hipFuncAttributeMaxDynamicSharedMemorySize, 133248);
        void* args[] = {(void*)&xp, (void*)&wpIF, (void*)&wpGO, (void*)&hb, (void*)&hpk};
        hipLaunchCooperativeKernel((const void*)k_lstm, dim3(256), dim3(256), args, 133248, stream);
    }
    // xp/wpIF/wpGO/hpk dead; overlay Pb/Qb/Gb/part/cv
    k_pack_w<<<5120, 256, 0, stream>>>(w_prior, Pb, 7);
    k_pack_w<<<2560, 256, 0, stream>>>(w_gen, Gb, 6);
    k_pack_q<<<10240, 256, 0, stream>>>(emb, Qb, cv);
    hipFuncSetAttribute((const void*)k_scores, hipFuncAttributeMaxDynamicSharedMemorySize, 131072);
    k_scores<<<512, 512, 131072, stream>>>(hb, zb, Pb, Qb, Gb, cv, b_prior, b_gen, part);
    k_gx<<<4096, 256, 0, stream>>>(z, x, w_gen, b_gen, gx);
    k_final<<<1, 256, 0, stream>>>(part, qz, gx, x_sl, (float*)d_out);
}

// Round 11
// 819.119 us; speedup vs baseline: 1.5569x; 1.5569x over previous
//
#include <hip/hip_runtime.h>
#include <hip/hip_bf16.h>
#include <math.h>

// Sizes fixed by the problem
#define BB 32
#define TT 128
#define KK 256
#define HH 512
#define VV 10000
#define VP 10240
#define BT 4096           // B*T
#define HLOG2PI 0.91893853320467274178f

// ---- workspace layout (float offsets) ----
// z       : 0          1048576   (BT*K, f32 — used by k_xp / k_gx)
// qz      : 1048576    4096
// hb      : 1052672    1048576 floats worth = BT*H bf16 (ushort)
// zb      : 2101248    524288 floats worth  = BT*K bf16 (ushort)
// gx      : 3149824    4096
// region  : 3252224    13117440
//  phase 1 (lstm): xp / wpIF / wpGO / hpk  (see offsets below)
//  phase 2 (scores), overlaying dead xp: Pb / Qb / Gb / part / cv

typedef short bf16x8 __attribute__((ext_vector_type(8)));
typedef float f32x4 __attribute__((ext_vector_type(4)));

__device__ __forceinline__ float softplus_b(float x) {
    float ax = fabsf(x);
    return fmaxf(x, 0.0f) + log2f(1.0f + exp2f(-ax));
}
__device__ __forceinline__ float sigm(float x) { return 1.0f / (1.0f + expf(-x)); }
// fast variants for the LSTM serial gate path (bf16-level accuracy is plenty)
__device__ __forceinline__ float fsigm(float x) { return 1.0f / (1.0f + __expf(-x)); }
__device__ __forceinline__ float ftanh(float x) {
    float e = __expf(2.0f * x);
    return 1.0f - 2.0f / (e + 1.0f);
}
__device__ __forceinline__ unsigned short f2bf(float f) {
    unsigned u = __float_as_uint(f);
    u += 0x7FFFu + ((u >> 16) & 1u);
    return (unsigned short)(u >> 16);
}
typedef _Float16 h2f16 __attribute__((ext_vector_type(2)));
__device__ __forceinline__ unsigned pkh2(float a, float b) {
    h2f16 h;
    h.x = (_Float16)a;
    h.y = (_Float16)b;
    return *(unsigned*)&h;
}
__device__ __forceinline__ float fdot2u(unsigned a, unsigned b, float c) {
    h2f16 ah = *(h2f16*)&a, bh = *(h2f16*)&b;
#if __has_builtin(__builtin_amdgcn_fdot2)
    return __builtin_amdgcn_fdot2(ah, bh, c, false);
#else
    return c + (float)ah.x * (float)bh.x + (float)ah.y * (float)bh.y;
#endif
}
// square a bf16x8 in-register: bf16->f32 is <<16; repack with v_cvt_pk_bf16_f32 (RNE)
__device__ __forceinline__ bf16x8 bsq(bf16x8 a) {
    union { bf16x8 v; unsigned w[4]; } u, r;
    u.v = a;
#pragma unroll
    for (int i = 0; i < 4; i++) {
        float lo = __uint_as_float(u.w[i] << 16);
        float hi = __uint_as_float(u.w[i] & 0xFFFF0000u);
        lo *= lo;
        hi *= hi;
        asm("v_cvt_pk_bf16_f32 %0, %1, %2" : "=v"(r.w[i]) : "v"(lo), "v"(hi));
    }
    return r.v;
}

// ---------------- 1) embedding -> z (f32 + bf16), q_z_lp ----------------
__global__ void k_embed(const int* __restrict__ x, const int* __restrict__ x_sl,
                        const float* __restrict__ eps, const float* __restrict__ emb,
                        float* __restrict__ z, ushort* __restrict__ zb,
                        float* __restrict__ qz) {
    int bt = blockIdx.x;
    int b = bt >> 7, t = bt & 127;
    int k = threadIdx.x;
    int xi = x[bt];
    float e1 = emb[xi * 512 + k];
    float sg = softplus_b(emb[xi * 512 + 256 + k]);
    float ep = eps[bt * 256 + k];
    float mk = (t < x_sl[b]) ? 1.f : 0.f;
    float zv = (e1 + sg * ep) * mk;
    z[bt * 256 + k] = zv;
    zb[bt * 256 + k] = f2bf(zv);
    float q = -HLOG2PI - logf(sg) - 0.5f * ep * ep;
    __shared__ float red[256];
    red[k] = q;
    __syncthreads();
    for (int s = 128; s > 0; s >>= 1) {
        if (k < s) red[k] += red[k + s];
        __syncthreads();
    }
    if (k == 0) qz[bt] = red[0];
}

// ---------------- 2) x_proj = z_shift @ w_ih^T + b_ih + b_hh ----------------
__global__ __launch_bounds__(256) void k_xp(const float* __restrict__ z,
                                            const float* __restrict__ w_ih,
                                            const float* __restrict__ b_ih,
                                            const float* __restrict__ b_hh,
                                            float* __restrict__ xp) {
    __shared__ float At[64][68];
    __shared__ float Wt[64][68];
    int n0 = blockIdx.x * 64, m0 = blockIdx.y * 64;
    int tid = threadIdx.x;
    int tn = tid & 15, tm = tid >> 4;
    float acc[4][4] = {};
    for (int kc = 0; kc < 256; kc += 64) {
        __syncthreads();
        for (int i = tid; i < 1024; i += 256) {
            int r = i >> 4, c4 = i & 15;
            int bt = m0 + r;
            int t = bt & 127;
            float4 v = make_float4(0.f, 0.f, 0.f, 0.f);
            if (t > 0) v = *(const float4*)(z + (bt - 1) * 256 + kc + c4 * 4);
            *(float4*)&At[r][c4 * 4] = v;
        }
        for (int i = tid; i < 1024; i += 256) {
            int r = i >> 4, c4 = i & 15;
            float4 v = *(const float4*)(w_ih + (n0 + r) * 256 + kc + c4 * 4);
            *(float4*)&Wt[r][c4 * 4] = v;
        }
        __syncthreads();
        for (int kk = 0; kk < 16; kk++) {
            float4 a[4], w[4];
#pragma unroll
            for (int i = 0; i < 4; i++) a[i] = *(const float4*)&At[tm + 16 * i][kk * 4];
#pragma unroll
            for (int j = 0; j < 4; j++) w[j] = *(const float4*)&Wt[tn + 16 * j][kk * 4];
#pragma unroll
            for (int i = 0; i < 4; i++)
#pragma unroll
                for (int j = 0; j < 4; j++)
                    acc[i][j] += a[i].x * w[j].x + a[i].y * w[j].y + a[i].z * w[j].z + a[i].w * w[j].w;
        }
    }
#pragma unroll
    for (int i = 0; i < 4; i++) {
        int m = m0 + tm + 16 * i;
#pragma unroll
        for (int j = 0; j < 4; j++) {
            int n = n0 + tn + 16 * j;
            xp[m * 2048 + n] = acc[i][j] + b_ih[n] + b_hh[n];
        }
    }
}

// ---------------- 2b) pack w_hh -> f16 pairs, layouts for k_lstm v2 ----------------
__global__ __launch_bounds__(256) void k_wpack2(const float* __restrict__ w_hh,
                                                uint4* __restrict__ wpIF,
                                                uint4* __restrict__ wpGO) {
    int o = blockIdx.x * 256 + threadIdx.x;  // 0..65535
    if (blockIdx.y == 0) {
        int kq = o & 3, j_local = (o >> 2) & 63, q = (o >> 8) & 31, m = o >> 13;
        int jg = (m << 6) + j_local;
        int k = (kq << 7) + (q << 2);
        const float* wi = w_hh + (size_t)jg * 512 + k;
        const float* wf = w_hh + (size_t)(512 + jg) * 512 + k;
        uint4 u;
        u.x = pkh2(wi[0], wi[1]); u.y = pkh2(wi[2], wi[3]);
        u.z = pkh2(wf[0], wf[1]); u.w = pkh2(wf[2], wf[3]);
        wpIF[o] = u;
    } else {
        int q = o & 31, kq = (o >> 5) & 3, j_local = (o >> 7) & 63, m = o >> 13;
        int jg = (m << 6) + j_local;
        int k = (kq << 7) + (q << 2);
        const float* wg = w_hh + (size_t)(1024 + jg) * 512 + k;
        const float* wo = w_hh + (size_t)(1536 + jg) * 512 + k;
        uint4 u;
        u.x = pkh2(wg[0], wg[1]); u.y = pkh2(wg[2], wg[3]);
        u.z = pkh2(wo[0], wo[1]); u.w = pkh2(wo[2], wo[3]);
        wpGO[o] = u;
    }
}

// ---------------- 3) LSTM v5: v6 loop body + skewed LDS bases only ----------------
// r10 post-mortem: v7/v8's restructured inner loop (uint4 hp4 + qq*2 indexing)
// dropped VGPR 96 -> 56 and SPILLED wgo[32] (128 regs) to scratch — FETCH
// 27 -> 543 MB, WRITE 8 -> 40 MB. That spill, not the poll, was the regression.
// v5 = EXACT v6 (348 us) loop body; the ONLY changes are the LDS base
// constants for the h exchange:
//   write slot tid + (tid>>6)*4 ; read base hbuf + kq*68
// -> read banks (4*kq + 2q) % 32: the 4 kq-groups hit distinct banks
//    (v6: all 4 on bank 2q = 4-way conflict, 5e7 cycles). Same loop shape
//    => same regalloc (VGPR ~96, wgo in regs/L2, no spill).
// Fast transcendentals kept (isolated in the kq==0 tail).
__global__ __launch_bounds__(256, 1) void k_lstm(const float* __restrict__ xp,
                                                 const uint4* __restrict__ wpIF,
                                                 const uint4* __restrict__ wpGO,
                                                 ushort* __restrict__ h_all,
                                                 unsigned* __restrict__ hpk) {
    extern __shared__ char smc[];
    uint4* wif = (uint4*)smc;                   // [q 32][wave-linear 256] = 128 KB
    unsigned* hs2 = (unsigned*)(smc + 131072);  // [2][272] dwords (skewed)
    int bid = blockIdx.x;
    int b = bid & 31;
    int m = bid >> 5;
    int tid = threadIdx.x;
    int w = tid >> 6, l = tid & 63;
    int jj = l >> 2, kq = l & 3;
    int j_local = (w << 4) + jj;
    int j_global = (m << 6) + j_local;
    const uint4* srcIF = wpIF + ((size_t)m << 13);
    for (int i = tid; i < 8192; i += 256) wif[i] = srcIF[i];
    uint4 wgo[32];
    const uint4* srcGO = wpGO + ((size_t)((((m << 6) + j_local) << 2) + kq) << 5);
#pragma unroll
    for (int q = 0; q < 32; q++) wgo[q] = srcGO[q];
    const uint4* wifp = wif + (w << 6) + l;
    int skslot = tid + ((tid >> 6) << 2);  // skewed write slot
    float c = 0.f;
    __syncthreads();
    for (int t = 0; t < 128; t++) {
        int bt = (b << 7) + t;
        float xg0 = 0.f, xg1 = 0.f, xg2 = 0.f, xg3 = 0.f;
        if (kq == 0) {  // prefetch xp before the poll (independent loads)
            const float* xpr = xp + (size_t)bt * 2048 + j_global;
            xg0 = xpr[0]; xg1 = xpr[512]; xg2 = xpr[1024]; xg3 = xpr[1536];
        }
        float a0 = 0.f, a1 = 0.f, a2 = 0.f, a3 = 0.f;
        if (t > 0) {
            const unsigned* src = hpk + ((size_t)(bt - 1) << 8);
            unsigned u;
            do {
                u = __hip_atomic_load(src + tid, __ATOMIC_RELAXED, __HIP_MEMORY_SCOPE_AGENT);
            } while (u == 0xFFFFFFFFu);
            unsigned* hbuf = hs2 + ((t - 1) & 1) * 272;
            hbuf[skslot] = u;
            __syncthreads();
            const unsigned* hp2 = hbuf + kq * 68;
#pragma unroll
            for (int q = 0; q < 32; q++) {
                uint4 A = wifp[q << 8];
                uint4 B = wgo[q];
                unsigned p0 = hp2[q << 1];
                unsigned p1 = hp2[(q << 1) + 1];
                a0 = fdot2u(A.x, p0, a0); a0 = fdot2u(A.y, p1, a0);
                a1 = fdot2u(A.z, p0, a1); a1 = fdot2u(A.w, p1, a1);
                a2 = fdot2u(B.x, p0, a2); a2 = fdot2u(B.y, p1, a2);
                a3 = fdot2u(B.z, p0, a3); a3 = fdot2u(B.w, p1, a3);
            }
#pragma unroll
            for (int off = 1; off <= 2; off <<= 1) {
                a0 += __shfl_xor(a0, off);
                a1 += __shfl_xor(a1, off);
                a2 += __shfl_xor(a2, off);
                a3 += __shfl_xor(a3, off);
            }
        }
        float h = 0.f;
        if (kq == 0) {
            float g0 = xg0 + a0, g1 = xg1 + a1, g2 = xg2 + a2, g3 = xg3 + a3;
            c = fsigm(g1) * c + fsigm(g0) * ftanh(g2);
            h = fsigm(g3) * ftanh(c);
            h_all[(size_t)bt * 512 + j_global] = f2bf(h);  // bf16, read post-kernel
        }
        float hp = __shfl_xor(h, 4);  // leader jj even <- h of jj+1
        if (kq == 0 && (jj & 1) == 0) {
            unsigned u = pkh2(h, hp);
            __hip_atomic_store(hpk + ((size_t)bt << 8) + (m << 5) + (w << 3) + (jj >> 1),
                               u, __ATOMIC_RELAXED, __HIP_MEMORY_SCOPE_AGENT);
        }
    }
}

// ---------------- 4a) cast weights -> bf16 row-major [v][K], pad rows zeroed ----------------
__global__ __launch_bounds__(256) void k_pack_w(const float* __restrict__ src,
                                                ushort* __restrict__ dst, int kshift) {
    int o = blockIdx.x * 256 + threadIdx.x;  // one ushort4 unit
    int c = o & ((1 << kshift) - 1);
    int r = o >> kshift;
    ushort4 u = make_ushort4(0, 0, 0, 0);
    if (r < VV) {
        float4 v = *(const float4*)(src + ((size_t)r << (kshift + 2)) + (c << 2));
        u = make_ushort4(f2bf(v.x), f2bf(v.y), f2bf(v.z), f2bf(v.w));
    }
    *(ushort4*)(dst + ((size_t)o << 2)) = u;
}

// ---------------- 4b) Qb rows [2*iv*mu (256) | -iv (256)] bf16 + const_v ----------------
__global__ void k_pack_q(const float* __restrict__ emb, ushort* __restrict__ Qb,
                         float* __restrict__ cv) {
    int v = blockIdx.x, k = threadIdx.x;
    if (v >= VV) {
        Qb[((size_t)v << 9) + k] = 0;
        Qb[((size_t)v << 9) + 256 + k] = 0;
        if (k == 0) cv[v] = 0.f;
        return;
    }
    float mu = emb[(size_t)v * 512 + k];
    float sg = softplus_b(emb[(size_t)v * 512 + 256 + k]);
    float iv = 0.5f / (sg * sg);
    Qb[((size_t)v << 9) + k] = f2bf(2.f * iv * mu);
    Qb[((size_t)v << 9) + 256 + k] = f2bf(-iv);
    float ct = -HLOG2PI - logf(sg) - mu * mu * iv;
    __shared__ float red[256];
    red[k] = ct;
    __syncthreads();
    for (int s = 128; s > 0; s >>= 1) {
        if (k < s) red[k] += red[k + s];
        __syncthreads();
    }
    if (k == 0) cv[v] = red[0];
}

// ---------------- 6) fused scores v6: ms=4 retile (B-reuse 2->4) ----------------
__global__ __launch_bounds__(512, 2) void k_scores(
    const ushort* __restrict__ hb, const ushort* __restrict__ zb,
    const ushort* __restrict__ Pb, const ushort* __restrict__ Qb,
    const ushort* __restrict__ Gb, const float* __restrict__ cv,
    const float* __restrict__ b_prior, const float* __restrict__ b_gen,
    float* __restrict__ part) {
    extern __shared__ ushort sm[];
    ushort* hT = sm;           // [kc 16][64 rows][32], swizzled granules = 64 KB
    ushort* fzT = sm + 32768;  // [kc 16][64 rows][32]: kc<8 z, kc>=8 z^2 = 64 KB
    int tid = threadIdx.x;
    int vs = blockIdx.x & 7;
    int mb = blockIdx.x >> 3;
    int bt0 = mb << 6;
    int vbase = vs * 1280;
    // stage h tile (64 x 512 bf16): pure 16B copies
    for (int i = tid; i < 4096; i += 512) {
        int quad = i & 3, row = (i >> 2) & 63, kc = i >> 8;
        uint4 v = *(const uint4*)(hb + (size_t)(bt0 + row) * 512 + kc * 32 + quad * 8);
        int g = (((row << 2) + (quad ^ (row & 3))) ^ (((row >> 2) & 1) << 2));
        *(uint4*)(hT + kc * 2048 + g * 8) = v;
    }
    // stage z (copy) + z^2 (bsq once per granule)
    for (int i = tid; i < 2048; i += 512) {
        int quad = i & 3, row = (i >> 2) & 63, kc = i >> 8;  // kc 0..7
        uint4 v = *(const uint4*)(zb + (size_t)(bt0 + row) * 256 + kc * 32 + quad * 8);
        int g = (((row << 2) + (quad ^ (row & 3))) ^ (((row >> 2) & 1) << 2));
        *(uint4*)(fzT + kc * 2048 + g * 8) = v;
        bf16x8 sq = bsq(*(bf16x8*)&v);
        *(uint4*)(fzT + (kc + 8) * 2048 + g * 8) = *(uint4*)&sq;
    }
    __syncthreads();
    int w = tid >> 6, l = tid & 63;
    int quad = l >> 4, ln = l & 15;
    int nq = w;  // wave: ALL 64 rows x cols nq*32..+32 per nt group
    const bf16x8* hT8 = (const bf16x8*)hT;
    const bf16x8* fz8 = (const bf16x8*)fzT;
    const bf16x8* Pb8 = (const bf16x8*)Pb;
    const bf16x8* Qb8 = (const bf16x8*)Qb;
    const bf16x8* Gb8 = (const bf16x8*)Gb;
    // ms=0 row = ln; ms adds 16 rows => granule g0 + 64*ms (swizzle-consistent)
    int g0 = (((ln << 2) + (quad ^ (ln & 3))) ^ (((ln >> 2) & 1) << 2));
    float Lm[3][16], Ls[3][16];
#pragma unroll
    for (int c = 0; c < 3; c++)
#pragma unroll
        for (int r = 0; r < 16; r++) { Lm[c][r] = -1e30f; Ls[c][r] = 0.f; }
#pragma unroll 1
    for (int nt = 0; nt < 5; nt++) {
        int n0 = vbase + (nt << 8) + (nq << 5);
        int rb = (n0 + ln) << 6;  // Pb/Qb granule row base (ns adds 1024)
        int rg = (n0 + ln) << 5;  // Gb granule row base (ns adds 512)
        __builtin_amdgcn_s_setprio(1);
        // ---- chain A: prior logits, h (K=512) vs Pb ----
        f32x4 accA[4][2];
#pragma unroll
        for (int ms = 0; ms < 4; ms++) { accA[ms][0] = 0.f; accA[ms][1] = 0.f; }
#pragma unroll 2
        for (int kc = 0; kc < 16; kc++) {
            bf16x8 b0 = Pb8[rb + (kc << 2) + quad];
            bf16x8 b1 = Pb8[rb + 1024 + (kc << 2) + quad];
#pragma unroll
            for (int ms = 0; ms < 4; ms++) {
                bf16x8 a = hT8[(kc << 8) + g0 + (ms << 6)];
                accA[ms][0] = __builtin_amdgcn_mfma_f32_16x16x32_bf16(a, b0, accA[ms][0], 0, 0, 0);
                accA[ms][1] = __builtin_amdgcn_mfma_f32_16x16x32_bf16(a, b1, accA[ms][1], 0, 0, 0);
            }
        }
        __builtin_amdgcn_s_setprio(0);
        // ---- epilogue A: LSE0; fold u1+cv into accB init ----
        f32x4 accB[4][2];
#pragma unroll
        for (int ns = 0; ns < 2; ns++) {
            int col = n0 + (ns << 4) + ln;
            bool ok = col < VV;
            float bpv = ok ? b_prior[col] : 0.f;
            float cvv = ok ? cv[col] : 0.f;
#pragma unroll
            for (int ms = 0; ms < 4; ms++)
#pragma unroll
                for (int r = 0; r < 4; r++) {
                    int r16 = (ms << 2) + r;
                    float u1 = ok ? accA[ms][ns][r] + bpv : -1e30f;
                    float nm = fmaxf(Lm[0][r16], u1);
                    Ls[0][r16] = Ls[0][r16] * __expf(Lm[0][r16] - nm) + __expf(u1 - nm);
                    Lm[0][r16] = nm;
                    accB[ms][ns][r] = ok ? u1 + cvv : -1e30f;  // pad Qb rows are 0
                }
        }
        __builtin_amdgcn_s_setprio(1);
        // ---- chain B: z (kc 0..7) + z^2 (kc 8..15) vs Qb ----
#pragma unroll 2
        for (int kc = 0; kc < 16; kc++) {
            bf16x8 bq0 = Qb8[rb + (kc << 2) + quad];
            bf16x8 bq1 = Qb8[rb + 1024 + (kc << 2) + quad];
#pragma unroll
            for (int ms = 0; ms < 4; ms++) {
                bf16x8 a = fz8[(kc << 8) + g0 + (ms << 6)];
                accB[ms][0] = __builtin_amdgcn_mfma_f32_16x16x32_bf16(a, bq0, accB[ms][0], 0, 0, 0);
                accB[ms][1] = __builtin_amdgcn_mfma_f32_16x16x32_bf16(a, bq1, accB[ms][1], 0, 0, 0);
            }
        }
        __builtin_amdgcn_s_setprio(0);
        // ---- epilogue B: LSE1 ----
#pragma unroll
        for (int ns = 0; ns < 2; ns++)
#pragma unroll
            for (int ms = 0; ms < 4; ms++)
#pragma unroll
                for (int r = 0; r < 4; r++) {
                    int r16 = (ms << 2) + r;
                    float u2 = accB[ms][ns][r];
                    float nm = fmaxf(Lm[1][r16], u2);
                    Ls[1][r16] = Ls[1][r16] * __expf(Lm[1][r16] - nm) + __expf(u2 - nm);
                    Lm[1][r16] = nm;
                }
        // ---- chain C: gen logits, z (K=256) vs Gb ----
        f32x4 accC[4][2];
#pragma unroll
        for (int ns = 0; ns < 2; ns++) {
            int col = n0 + (ns << 4) + ln;
            bool ok = col < VV;
            float bgv = ok ? b_gen[col] : -1e30f;  // pad Gb rows are 0
#pragma unroll
            for (int ms = 0; ms < 4; ms++) accC[ms][ns] = bgv;
        }
        __builtin_amdgcn_s_setprio(1);
#pragma unroll 2
        for (int kc = 0; kc < 8; kc++) {
            bf16x8 bg0 = Gb8[rg + (kc << 2) + quad];
            bf16x8 bg1 = Gb8[rg + 512 + (kc << 2) + quad];
#pragma unroll
            for (int ms = 0; ms < 4; ms++) {
                bf16x8 a = fz8[(kc << 8) + g0 + (ms << 6)];
                accC[ms][0] = __builtin_amdgcn_mfma_f32_16x16x32_bf16(a, bg0, accC[ms][0], 0, 0, 0);
                accC[ms][1] = __builtin_amdgcn_mfma_f32_16x16x32_bf16(a, bg1, accC[ms][1], 0, 0, 0);
            }
        }
        __builtin_amdgcn_s_setprio(0);
        // ---- epilogue C: LSE2 ----
#pragma unroll
        for (int ns = 0; ns < 2; ns++)
#pragma unroll
            for (int ms = 0; ms < 4; ms++)
#pragma unroll
                for (int r = 0; r < 4; r++) {
                    int r16 = (ms << 2) + r;
                    float u3 = accC[ms][ns][r];
                    float nm = fmaxf(Lm[2][r16], u3);
                    Ls[2][r16] = Ls[2][r16] * __expf(Lm[2][r16] - nm) + __expf(u3 - nm);
                    Lm[2][r16] = nm;
                }
    }
    // merge across the 16 col-lanes (same rows; xor of low-4 bits keeps quad)
#pragma unroll
    for (int off = 1; off <= 8; off <<= 1)
#pragma unroll
        for (int c = 0; c < 3; c++)
#pragma unroll
            for (int r16 = 0; r16 < 16; r16++) {
                float mo = __shfl_xor(Lm[c][r16], off);
                float so = __shfl_xor(Ls[c][r16], off);
                float nm = fmaxf(Lm[c][r16], mo);
                Ls[c][r16] = Ls[c][r16] * __expf(Lm[c][r16] - nm) + so * __expf(mo - nm);
                Lm[c][r16] = nm;
            }
    // block-level merge across the 8 wave column-slices (staging LDS dead now)
    __syncthreads();
    float* bm = (float*)sm;  // [3][8 w][64 rows]
    float* bs = bm + 1536;
    if (ln == 0) {
#pragma unroll
        for (int c = 0; c < 3; c++)
#pragma unroll
            for (int r16 = 0; r16 < 16; r16++) {
                int row = ((r16 >> 2) << 4) + (quad << 2) + (r16 & 3);
                bm[(c * 8 + w) * 64 + row] = Lm[c][r16];
                bs[(c * 8 + w) * 64 + row] = Ls[c][r16];
            }
    }
    __syncthreads();
    if (tid < 192) {
        int c = tid >> 6, row = tid & 63;
        float M = -1e30f, S = 0.f;
#pragma unroll
        for (int q = 0; q < 8; q++) {
            float m = bm[(c * 8 + q) * 64 + row];
            float s = bs[(c * 8 + q) * 64 + row];
            float Mn = fmaxf(M, m);
            S = S * __expf(M - Mn) + s * __expf(m - Mn);
            M = Mn;
        }
        part[(vs * 6 + c * 2) * 4096 + bt0 + row] = M;
        part[(vs * 6 + c * 2 + 1) * 4096 + bt0 + row] = S;
    }
}

// ---------------- 7) gx = z . w_gen[x] + b_gen[x] ----------------
__global__ void k_gx(const float* __restrict__ z, const int* __restrict__ x,
                     const float* __restrict__ w_gen, const float* __restrict__ b_gen,
                     float* __restrict__ gx) {
    int bt = blockIdx.x, k = threadIdx.x;
    int xi = x[bt];
    float p = z[bt * 256 + k] * w_gen[xi * 256 + k];
    __shared__ float red[256];
    red[k] = p;
    __syncthreads();
    for (int s = 128; s > 0; s >>= 1) {
        if (k < s) red[k] += red[k + s];
        __syncthreads();
    }
    if (k == 0) gx[bt] = red[0] + b_gen[xi];
}

// ---------------- 8) finalize (merge 8 V-split partials) ----------------
__device__ __forceinline__ float lse8(const float* __restrict__ part, int comp, int bt) {
    float M = -1e30f, S = 0.f;
#pragma unroll
    for (int vsi = 0; vsi < 8; vsi++) {
        float m = part[(vsi * 6 + comp) * 4096 + bt];
        float s = part[(vsi * 6 + comp + 1) * 4096 + bt];
        float Mn = fmaxf(M, m);
        S = S * __expf(M - Mn) + s * __expf(m - Mn);
        M = Mn;
    }
    return M + logf(S);
}

__global__ void k_final(const float* __restrict__ part, const float* __restrict__ qz,
                        const float* __restrict__ gxv, const int* __restrict__ x_sl,
                        float* __restrict__ out) {
    int tid = threadIdx.x;
    float S = 0.f;
    for (int bt = tid; bt < 4096; bt += 256) {
        int b = bt >> 7, t = bt & 127;
        if (t < x_sl[b]) {
            float lse1 = lse8(part, 0, bt);
            float lse2 = lse8(part, 2, bt);
            float lse3 = lse8(part, 4, bt);
            float p_z = lse2 - lse1;
            float kl = qz[bt] - p_z;
            float px = gxv[bt] - lse3;
            S += px - kl;
        }
    }
    __shared__ float red[256];
    red[tid] = S;
    __syncthreads();
    for (int s = 128; s > 0; s >>= 1) {
        if (tid < s) red[tid] += red[tid + s];
        __syncthreads();
    }
    if (tid == 0) {
        int sl = 0;
        for (int b = 0; b < 32; b++) sl += x_sl[b];
        out[0] = -(red[0] / (float)sl);
    }
}

extern "C" void kernel_launch(void* const* d_in, const int* in_sizes, int n_in,
                              void* d_out, int out_size, void* d_ws, size_t ws_size,
                              hipStream_t stream) {
    const int* x = (const int*)d_in[0];
    const int* x_sl = (const int*)d_in[1];
    const float* eps = (const float*)d_in[2];
    const float* emb = (const float*)d_in[3];
    const float* w_ih = (const float*)d_in[4];
    const float* w_hh = (const float*)d_in[5];
    const float* b_ih = (const float*)d_in[6];
    const float* b_hh = (const float*)d_in[7];
    const float* w_prior = (const float*)d_in[8];
    const float* b_prior = (const float*)d_in[9];
    const float* w_gen = (const float*)d_in[10];
    const float* b_gen = (const float*)d_in[11];

    float* ws = (float*)d_ws;
    float* z = ws;
    float* qz = ws + 1048576;
    ushort* hb = (ushort*)(ws + 1052672);            // BT*H bf16 = 4 MB
    ushort* zb = (ushort*)(ws + 1052672 + 1048576);  // BT*K bf16 = 2 MB
    float* gx = ws + 3149824;
    float* region = ws + 3252224;
    float* xp = region;
    uint4* wpIF = (uint4*)(region + 8388608);
    uint4* wpGO = wpIF + 65536;
    unsigned* hpk = (unsigned*)(region + 8912896);  // 1048576 dwords
    ushort* Pb = (ushort*)(region);                 // phase 2 (xp dead)
    ushort* Qb = (ushort*)(region + 2621440);
    ushort* Gb = (ushort*)(region + 5242880);
    float* part = region + 6553600;                 // 8*6*4096
    float* cv = region + 13107200;

    k_embed<<<4096, 256, 0, stream>>>(x, x_sl, eps, emb, z, zb, qz);
    k_xp<<<dim3(32, 64), 256, 0, stream>>>(z, w_ih, b_ih, b_hh, xp);
    k_wpack2<<<dim3(256, 2), 256, 0, stream>>>(w_hh, wpIF, wpGO);
    hipMemsetAsync(hpk, 0xFF, 4194304, stream);  // sentinel: f16 NaN pairs
    {
        hipFuncSetAttribute((const void*)k_lstm, hipFuncAttributeMaxDynamicSharedMemorySize, 133248);
        void* args[] = {(void*)&xp, (void*)&wpIF, (void*)&wpGO, (void*)&hb, (void*)&hpk};
        hipLaunchCooperativeKernel((const void*)k_lstm, dim3(256), dim3(256), args, 133248, stream);
    }
    // xp/wpIF/wpGO/hpk dead; overlay Pb/Qb/Gb/part/cv
    k_pack_w<<<5120, 256, 0, stream>>>(w_prior, Pb, 7);
    k_pack_w<<<2560, 256, 0, stream>>>(w_gen, Gb, 6);
    k_pack_q<<<10240, 256, 0, stream>>>(emb, Qb, cv);
    hipFuncSetAttribute((const void*)k_scores, hipFuncAttributeMaxDynamicSharedMemorySize, 131072);
    k_scores<<<512, 512, 131072, stream>>>(hb, zb, Pb, Qb, Gb, cv, b_prior, b_gen, part);
    k_gx<<<4096, 256, 0, stream>>>(z, x, w_gen, b_gen, gx);
    k_final<<<1, 256, 0, stream>>>(part, qz, gx, x_sl, (float*)d_out);
}

// Round 12
// 761.046 us; speedup vs baseline: 1.6757x; 1.0763x over previous
//
#include <hip/hip_runtime.h>
#include <hip/hip_bf16.h>
#include <math.h>

// Sizes fixed by the problem
#define BB 32
#define TT 128
#define KK 256
#define HH 512
#define VV 10000
#define VP 10240
#define BT 4096           // B*T
#define HLOG2PI 0.91893853320467274178f

// ---- workspace layout (float offsets) ----
// z       : 0          1048576   (BT*K, f32 — used by k_gx)
// qz      : 1048576    4096
// hb      : 1052672    1048576 floats worth = BT*H bf16 (ushort)
// zb      : 2101248    524288 floats worth  = BT*K bf16 (ushort)
// gx      : 3149824    4096
// region  : 3252224    13117440
//  phase 1 (lstm): xp(0..8388608) wpIF(+8388608) wpGO(+8650752)
//                  hpk(+8912896, 1048576 dwords) wb(+9961472, 524288 ushorts)
//  phase 2 (scores), overlaying dead xp: Pb / Qb / Gb / part / cv

typedef short bf16x8 __attribute__((ext_vector_type(8)));
typedef float f32x4 __attribute__((ext_vector_type(4)));

__device__ __forceinline__ float softplus_b(float x) {
    float ax = fabsf(x);
    return fmaxf(x, 0.0f) + log2f(1.0f + exp2f(-ax));
}
__device__ __forceinline__ float sigm(float x) { return 1.0f / (1.0f + expf(-x)); }
// fast variants for the LSTM serial gate path (bf16-level accuracy is plenty)
__device__ __forceinline__ float fsigm(float x) { return 1.0f / (1.0f + __expf(-x)); }
__device__ __forceinline__ float ftanh(float x) {
    float e = __expf(2.0f * x);
    return 1.0f - 2.0f / (e + 1.0f);
}
__device__ __forceinline__ unsigned short f2bf(float f) {
    unsigned u = __float_as_uint(f);
    u += 0x7FFFu + ((u >> 16) & 1u);
    return (unsigned short)(u >> 16);
}
typedef _Float16 h2f16 __attribute__((ext_vector_type(2)));
__device__ __forceinline__ unsigned pkh2(float a, float b) {
    h2f16 h;
    h.x = (_Float16)a;
    h.y = (_Float16)b;
    return *(unsigned*)&h;
}
__device__ __forceinline__ float fdot2u(unsigned a, unsigned b, float c) {
    h2f16 ah = *(h2f16*)&a, bh = *(h2f16*)&b;
#if __has_builtin(__builtin_amdgcn_fdot2)
    return __builtin_amdgcn_fdot2(ah, bh, c, false);
#else
    return c + (float)ah.x * (float)bh.x + (float)ah.y * (float)bh.y;
#endif
}
// square a bf16x8 in-register: bf16->f32 is <<16; repack with v_cvt_pk_bf16_f32 (RNE)
__device__ __forceinline__ bf16x8 bsq(bf16x8 a) {
    union { bf16x8 v; unsigned w[4]; } u, r;
    u.v = a;
#pragma unroll
    for (int i = 0; i < 4; i++) {
        float lo = __uint_as_float(u.w[i] << 16);
        float hi = __uint_as_float(u.w[i] & 0xFFFF0000u);
        lo *= lo;
        hi *= hi;
        asm("v_cvt_pk_bf16_f32 %0, %1, %2" : "=v"(r.w[i]) : "v"(lo), "v"(hi));
    }
    return r.v;
}

// ---------------- 1) embedding -> z (f32 + bf16), q_z_lp ----------------
__global__ void k_embed(const int* __restrict__ x, const int* __restrict__ x_sl,
                        const float* __restrict__ eps, const float* __restrict__ emb,
                        float* __restrict__ z, ushort* __restrict__ zb,
                        float* __restrict__ qz) {
    int bt = blockIdx.x;
    int b = bt >> 7, t = bt & 127;
    int k = threadIdx.x;
    int xi = x[bt];
    float e1 = emb[xi * 512 + k];
    float sg = softplus_b(emb[xi * 512 + 256 + k]);
    float ep = eps[bt * 256 + k];
    float mk = (t < x_sl[b]) ? 1.f : 0.f;
    float zv = (e1 + sg * ep) * mk;
    z[bt * 256 + k] = zv;
    zb[bt * 256 + k] = f2bf(zv);
    float q = -HLOG2PI - logf(sg) - 0.5f * ep * ep;
    __shared__ float red[256];
    red[k] = q;
    __syncthreads();
    for (int s = 128; s > 0; s >>= 1) {
        if (k < s) red[k] += red[k + s];
        __syncthreads();
    }
    if (k == 0) qz[bt] = red[0];
}

// ---------------- 2) x_proj via MFMA: xp = z_shift @ w_ih^T + b_ih + b_hh ----------------
// Replaces the fp32 SIMD k_xp (~4.3 GFLOP at ~50 TF ≈ 90 us) with the proven
// k_scores machinery: same granule swizzle, same ms=4/ns=2 wave tile.
// 512 blocks = 64 m-tiles x 8 n-groups; 8 waves; A (z_shift bf16) staged in
// 32 KB LDS; B = wb (w_ih bf16, packed by k_pack_w kshift=6); bias in acc init.
__global__ __launch_bounds__(512) void k_xpm(const ushort* __restrict__ zb,
                                             const ushort* __restrict__ wb,
                                             const float* __restrict__ b_ih,
                                             const float* __restrict__ b_hh,
                                             float* __restrict__ xp) {
    __shared__ ushort zs[16384];  // [kc 8][256 granules of 16B], swizzled
    int tid = threadIdx.x;
    int mb = blockIdx.x >> 3;
    int nb = blockIdx.x & 7;
    int bt0 = mb << 6;
    int n0base = nb << 8;
    // stage A: z_shift rows bt0..bt0+63 (t==0 -> zeros), bf16 16B copies
    for (int i = tid; i < 2048; i += 512) {
        int quad = i & 3, row = (i >> 2) & 63, kc = i >> 8;  // kc 0..7
        int bt = bt0 + row;
        uint4 v = make_uint4(0, 0, 0, 0);
        if ((bt & 127) != 0)
            v = *(const uint4*)(zb + (size_t)(bt - 1) * 256 + kc * 32 + quad * 8);
        int g = (((row << 2) + (quad ^ (row & 3))) ^ (((row >> 2) & 1) << 2));
        *(uint4*)(zs + kc * 2048 + g * 8) = v;
    }
    __syncthreads();
    int w = tid >> 6, l = tid & 63;
    int quad = l >> 4, ln = l & 15;
    int n0 = n0base + (w << 5);
    const bf16x8* zs8 = (const bf16x8*)zs;
    const bf16x8* wb8 = (const bf16x8*)wb;
    int g0 = (((ln << 2) + (quad ^ (ln & 3))) ^ (((ln >> 2) & 1) << 2));
    int rb = (n0 + ln) << 5;  // wb granule row base (32 granules/row; ns adds 512)
    f32x4 acc[4][2];
#pragma unroll
    for (int ns = 0; ns < 2; ns++) {
        int col = n0 + (ns << 4) + ln;
        float bias = b_ih[col] + b_hh[col];
#pragma unroll
        for (int ms = 0; ms < 4; ms++) acc[ms][ns] = bias;
    }
#pragma unroll
    for (int kc = 0; kc < 8; kc++) {
        bf16x8 b0 = wb8[rb + (kc << 2) + quad];
        bf16x8 b1 = wb8[rb + 512 + (kc << 2) + quad];
#pragma unroll
        for (int ms = 0; ms < 4; ms++) {
            bf16x8 a = zs8[(kc << 8) + g0 + (ms << 6)];
            acc[ms][0] = __builtin_amdgcn_mfma_f32_16x16x32_bf16(a, b0, acc[ms][0], 0, 0, 0);
            acc[ms][1] = __builtin_amdgcn_mfma_f32_16x16x32_bf16(a, b1, acc[ms][1], 0, 0, 0);
        }
    }
    // write: row = 16*ms + 4*quad + r, col = n0 + 16*ns + ln
#pragma unroll
    for (int ms = 0; ms < 4; ms++)
#pragma unroll
        for (int ns = 0; ns < 2; ns++)
#pragma unroll
            for (int r = 0; r < 4; r++) {
                int row = bt0 + (ms << 4) + (quad << 2) + r;
                xp[(size_t)row * 2048 + n0 + (ns << 4) + ln] = acc[ms][ns][r];
            }
}

// ---------------- 2b) pack w_hh -> f16 pairs, layouts for k_lstm v2 ----------------
__global__ __launch_bounds__(256) void k_wpack2(const float* __restrict__ w_hh,
                                                uint4* __restrict__ wpIF,
                                                uint4* __restrict__ wpGO) {
    int o = blockIdx.x * 256 + threadIdx.x;  // 0..65535
    if (blockIdx.y == 0) {
        int kq = o & 3, j_local = (o >> 2) & 63, q = (o >> 8) & 31, m = o >> 13;
        int jg = (m << 6) + j_local;
        int k = (kq << 7) + (q << 2);
        const float* wi = w_hh + (size_t)jg * 512 + k;
        const float* wf = w_hh + (size_t)(512 + jg) * 512 + k;
        uint4 u;
        u.x = pkh2(wi[0], wi[1]); u.y = pkh2(wi[2], wi[3]);
        u.z = pkh2(wf[0], wf[1]); u.w = pkh2(wf[2], wf[3]);
        wpIF[o] = u;
    } else {
        int q = o & 31, kq = (o >> 5) & 3, j_local = (o >> 7) & 63, m = o >> 13;
        int jg = (m << 6) + j_local;
        int k = (kq << 7) + (q << 2);
        const float* wg = w_hh + (size_t)(1024 + jg) * 512 + k;
        const float* wo = w_hh + (size_t)(1536 + jg) * 512 + k;
        uint4 u;
        u.x = pkh2(wg[0], wg[1]); u.y = pkh2(wg[2], wg[3]);
        u.z = pkh2(wo[0], wo[1]); u.w = pkh2(wo[2], wo[3]);
        wpGO[o] = u;
    }
}

// ---------------- 3) LSTM v5: v6 loop body + skewed LDS bases only ----------------
__global__ __launch_bounds__(256, 1) void k_lstm(const float* __restrict__ xp,
                                                 const uint4* __restrict__ wpIF,
                                                 const uint4* __restrict__ wpGO,
                                                 ushort* __restrict__ h_all,
                                                 unsigned* __restrict__ hpk) {
    extern __shared__ char smc[];
    uint4* wif = (uint4*)smc;                   // [q 32][wave-linear 256] = 128 KB
    unsigned* hs2 = (unsigned*)(smc + 131072);  // [2][272] dwords (skewed)
    int bid = blockIdx.x;
    int b = bid & 31;
    int m = bid >> 5;
    int tid = threadIdx.x;
    int w = tid >> 6, l = tid & 63;
    int jj = l >> 2, kq = l & 3;
    int j_local = (w << 4) + jj;
    int j_global = (m << 6) + j_local;
    const uint4* srcIF = wpIF + ((size_t)m << 13);
    for (int i = tid; i < 8192; i += 256) wif[i] = srcIF[i];
    uint4 wgo[32];
    const uint4* srcGO = wpGO + ((size_t)((((m << 6) + j_local) << 2) + kq) << 5);
#pragma unroll
    for (int q = 0; q < 32; q++) wgo[q] = srcGO[q];
    const uint4* wifp = wif + (w << 6) + l;
    int skslot = tid + ((tid >> 6) << 2);  // skewed write slot
    float c = 0.f;
    __syncthreads();
    for (int t = 0; t < 128; t++) {
        int bt = (b << 7) + t;
        float xg0 = 0.f, xg1 = 0.f, xg2 = 0.f, xg3 = 0.f;
        if (kq == 0) {  // prefetch xp before the poll (independent loads)
            const float* xpr = xp + (size_t)bt * 2048 + j_global;
            xg0 = xpr[0]; xg1 = xpr[512]; xg2 = xpr[1024]; xg3 = xpr[1536];
        }
        float a0 = 0.f, a1 = 0.f, a2 = 0.f, a3 = 0.f;
        if (t > 0) {
            const unsigned* src = hpk + ((size_t)(bt - 1) << 8);
            unsigned u;
            do {
                u = __hip_atomic_load(src + tid, __ATOMIC_RELAXED, __HIP_MEMORY_SCOPE_AGENT);
            } while (u == 0xFFFFFFFFu);
            unsigned* hbuf = hs2 + ((t - 1) & 1) * 272;
            hbuf[skslot] = u;
            __syncthreads();
            const unsigned* hp2 = hbuf + kq * 68;
#pragma unroll
            for (int q = 0; q < 32; q++) {
                uint4 A = wifp[q << 8];
                uint4 B = wgo[q];
                unsigned p0 = hp2[q << 1];
                unsigned p1 = hp2[(q << 1) + 1];
                a0 = fdot2u(A.x, p0, a0); a0 = fdot2u(A.y, p1, a0);
                a1 = fdot2u(A.z, p0, a1); a1 = fdot2u(A.w, p1, a1);
                a2 = fdot2u(B.x, p0, a2); a2 = fdot2u(B.y, p1, a2);
                a3 = fdot2u(B.z, p0, a3); a3 = fdot2u(B.w, p1, a3);
            }
#pragma unroll
            for (int off = 1; off <= 2; off <<= 1) {
                a0 += __shfl_xor(a0, off);
                a1 += __shfl_xor(a1, off);
                a2 += __shfl_xor(a2, off);
                a3 += __shfl_xor(a3, off);
            }
        }
        float h = 0.f;
        if (kq == 0) {
            float g0 = xg0 + a0, g1 = xg1 + a1, g2 = xg2 + a2, g3 = xg3 + a3;
            c = fsigm(g1) * c + fsigm(g0) * ftanh(g2);
            h = fsigm(g3) * ftanh(c);
            h_all[(size_t)bt * 512 + j_global] = f2bf(h);  // bf16, read post-kernel
        }
        float hp = __shfl_xor(h, 4);  // leader jj even <- h of jj+1
        if (kq == 0 && (jj & 1) == 0) {
            unsigned u = pkh2(h, hp);
            __hip_atomic_store(hpk + ((size_t)bt << 8) + (m << 5) + (w << 3) + (jj >> 1),
                               u, __ATOMIC_RELAXED, __HIP_MEMORY_SCOPE_AGENT);
        }
    }
}

// ---------------- 4a) cast weights -> bf16 row-major [v][2^kshift granules] ----------------
// Also used for w_ih (kshift=6, 2048 rows < VV so no padding path).
__global__ __launch_bounds__(256) void k_pack_w(const float* __restrict__ src,
                                                ushort* __restrict__ dst, int kshift) {
    int o = blockIdx.x * 256 + threadIdx.x;  // one ushort4 unit
    int c = o & ((1 << kshift) - 1);
    int r = o >> kshift;
    ushort4 u = make_ushort4(0, 0, 0, 0);
    if (r < VV) {
        float4 v = *(const float4*)(src + ((size_t)r << (kshift + 2)) + (c << 2));
        u = make_ushort4(f2bf(v.x), f2bf(v.y), f2bf(v.z), f2bf(v.w));
    }
    *(ushort4*)(dst + ((size_t)o << 2)) = u;
}

// ---------------- 4b) Qb rows [2*iv*mu (256) | -iv (256)] bf16 + const_v ----------------
__global__ void k_pack_q(const float* __restrict__ emb, ushort* __restrict__ Qb,
                         float* __restrict__ cv) {
    int v = blockIdx.x, k = threadIdx.x;
    if (v >= VV) {
        Qb[((size_t)v << 9) + k] = 0;
        Qb[((size_t)v << 9) + 256 + k] = 0;
        if (k == 0) cv[v] = 0.f;
        return;
    }
    float mu = emb[(size_t)v * 512 + k];
    float sg = softplus_b(emb[(size_t)v * 512 + 256 + k]);
    float iv = 0.5f / (sg * sg);
    Qb[((size_t)v << 9) + k] = f2bf(2.f * iv * mu);
    Qb[((size_t)v << 9) + 256 + k] = f2bf(-iv);
    float ct = -HLOG2PI - logf(sg) - mu * mu * iv;
    __shared__ float red[256];
    red[k] = ct;
    __syncthreads();
    for (int s = 128; s > 0; s >>= 1) {
        if (k < s) red[k] += red[k + s];
        __syncthreads();
    }
    if (k == 0) cv[v] = red[0];
}

// ---------------- 6) fused scores v6: ms=4 retile (B-reuse 2->4) ----------------
__global__ __launch_bounds__(512, 2) void k_scores(
    const ushort* __restrict__ hb, const ushort* __restrict__ zb,
    const ushort* __restrict__ Pb, const ushort* __restrict__ Qb,
    const ushort* __restrict__ Gb, const float* __restrict__ cv,
    const float* __restrict__ b_prior, const float* __restrict__ b_gen,
    float* __restrict__ part) {
    extern __shared__ ushort sm[];
    ushort* hT = sm;           // [kc 16][64 rows][32], swizzled granules = 64 KB
    ushort* fzT = sm + 32768;  // [kc 16][64 rows][32]: kc<8 z, kc>=8 z^2 = 64 KB
    int tid = threadIdx.x;
    int vs = blockIdx.x & 7;
    int mb = blockIdx.x >> 3;
    int bt0 = mb << 6;
    int vbase = vs * 1280;
    // stage h tile (64 x 512 bf16): pure 16B copies
    for (int i = tid; i < 4096; i += 512) {
        int quad = i & 3, row = (i >> 2) & 63, kc = i >> 8;
        uint4 v = *(const uint4*)(hb + (size_t)(bt0 + row) * 512 + kc * 32 + quad * 8);
        int g = (((row << 2) + (quad ^ (row & 3))) ^ (((row >> 2) & 1) << 2));
        *(uint4*)(hT + kc * 2048 + g * 8) = v;
    }
    // stage z (copy) + z^2 (bsq once per granule)
    for (int i = tid; i < 2048; i += 512) {
        int quad = i & 3, row = (i >> 2) & 63, kc = i >> 8;  // kc 0..7
        uint4 v = *(const uint4*)(zb + (size_t)(bt0 + row) * 256 + kc * 32 + quad * 8);
        int g = (((row << 2) + (quad ^ (row & 3))) ^ (((row >> 2) & 1) << 2));
        *(uint4*)(fzT + kc * 2048 + g * 8) = v;
        bf16x8 sq = bsq(*(bf16x8*)&v);
        *(uint4*)(fzT + (kc + 8) * 2048 + g * 8) = *(uint4*)&sq;
    }
    __syncthreads();
    int w = tid >> 6, l = tid & 63;
    int quad = l >> 4, ln = l & 15;
    int nq = w;  // wave: ALL 64 rows x cols nq*32..+32 per nt group
    const bf16x8* hT8 = (const bf16x8*)hT;
    const bf16x8* fz8 = (const bf16x8*)fzT;
    const bf16x8* Pb8 = (const bf16x8*)Pb;
    const bf16x8* Qb8 = (const bf16x8*)Qb;
    const bf16x8* Gb8 = (const bf16x8*)Gb;
    // ms=0 row = ln; ms adds 16 rows => granule g0 + 64*ms (swizzle-consistent)
    int g0 = (((ln << 2) + (quad ^ (ln & 3))) ^ (((ln >> 2) & 1) << 2));
    float Lm[3][16], Ls[3][16];
#pragma unroll
    for (int c = 0; c < 3; c++)
#pragma unroll
        for (int r = 0; r < 16; r++) { Lm[c][r] = -1e30f; Ls[c][r] = 0.f; }
#pragma unroll 1
    for (int nt = 0; nt < 5; nt++) {
        int n0 = vbase + (nt << 8) + (nq << 5);
        int rb = (n0 + ln) << 6;  // Pb/Qb granule row base (ns adds 1024)
        int rg = (n0 + ln) << 5;  // Gb granule row base (ns adds 512)
        __builtin_amdgcn_s_setprio(1);
        // ---- chain A: prior logits, h (K=512) vs Pb ----
        f32x4 accA[4][2];
#pragma unroll
        for (int ms = 0; ms < 4; ms++) { accA[ms][0] = 0.f; accA[ms][1] = 0.f; }
#pragma unroll 2
        for (int kc = 0; kc < 16; kc++) {
            bf16x8 b0 = Pb8[rb + (kc << 2) + quad];
            bf16x8 b1 = Pb8[rb + 1024 + (kc << 2) + quad];
#pragma unroll
            for (int ms = 0; ms < 4; ms++) {
                bf16x8 a = hT8[(kc << 8) + g0 + (ms << 6)];
                accA[ms][0] = __builtin_amdgcn_mfma_f32_16x16x32_bf16(a, b0, accA[ms][0], 0, 0, 0);
                accA[ms][1] = __builtin_amdgcn_mfma_f32_16x16x32_bf16(a, b1, accA[ms][1], 0, 0, 0);
            }
        }
        __builtin_amdgcn_s_setprio(0);
        // ---- epilogue A: LSE0; fold u1+cv into accB init ----
        f32x4 accB[4][2];
#pragma unroll
        for (int ns = 0; ns < 2; ns++) {
            int col = n0 + (ns << 4) + ln;
            bool ok = col < VV;
            float bpv = ok ? b_prior[col] : 0.f;
            float cvv = ok ? cv[col] : 0.f;
#pragma unroll
            for (int ms = 0; ms < 4; ms++)
#pragma unroll
                for (int r = 0; r < 4; r++) {
                    int r16 = (ms << 2) + r;
                    float u1 = ok ? accA[ms][ns][r] + bpv : -1e30f;
                    float nm = fmaxf(Lm[0][r16], u1);
                    Ls[0][r16] = Ls[0][r16] * __expf(Lm[0][r16] - nm) + __expf(u1 - nm);
                    Lm[0][r16] = nm;
                    accB[ms][ns][r] = ok ? u1 + cvv : -1e30f;  // pad Qb rows are 0
                }
        }
        __builtin_amdgcn_s_setprio(1);
        // ---- chain B: z (kc 0..7) + z^2 (kc 8..15) vs Qb ----
#pragma unroll 2
        for (int kc = 0; kc < 16; kc++) {
            bf16x8 bq0 = Qb8[rb + (kc << 2) + quad];
            bf16x8 bq1 = Qb8[rb + 1024 + (kc << 2) + quad];
#pragma unroll
            for (int ms = 0; ms < 4; ms++) {
                bf16x8 a = fz8[(kc << 8) + g0 + (ms << 6)];
                accB[ms][0] = __builtin_amdgcn_mfma_f32_16x16x32_bf16(a, bq0, accB[ms][0], 0, 0, 0);
                accB[ms][1] = __builtin_amdgcn_mfma_f32_16x16x32_bf16(a, bq1, accB[ms][1], 0, 0, 0);
            }
        }
        __builtin_amdgcn_s_setprio(0);
        // ---- epilogue B: LSE1 ----
#pragma unroll
        for (int ns = 0; ns < 2; ns++)
#pragma unroll
            for (int ms = 0; ms < 4; ms++)
#pragma unroll
                for (int r = 0; r < 4; r++) {
                    int r16 = (ms << 2) + r;
                    float u2 = accB[ms][ns][r];
                    float nm = fmaxf(Lm[1][r16], u2);
                    Ls[1][r16] = Ls[1][r16] * __expf(Lm[1][r16] - nm) + __expf(u2 - nm);
                    Lm[1][r16] = nm;
                }
        // ---- chain C: gen logits, z (K=256) vs Gb ----
        f32x4 accC[4][2];
#pragma unroll
        for (int ns = 0; ns < 2; ns++) {
            int col = n0 + (ns << 4) + ln;
            bool ok = col < VV;
            float bgv = ok ? b_gen[col] : -1e30f;  // pad Gb rows are 0
#pragma unroll
            for (int ms = 0; ms < 4; ms++) accC[ms][ns] = bgv;
        }
        __builtin_amdgcn_s_setprio(1);
#pragma unroll 2
        for (int kc = 0; kc < 8; kc++) {
            bf16x8 bg0 = Gb8[rg + (kc << 2) + quad];
            bf16x8 bg1 = Gb8[rg + 512 + (kc << 2) + quad];
#pragma unroll
            for (int ms = 0; ms < 4; ms++) {
                bf16x8 a = fz8[(kc << 8) + g0 + (ms << 6)];
                accC[ms][0] = __builtin_amdgcn_mfma_f32_16x16x32_bf16(a, bg0, accC[ms][0], 0, 0, 0);
                accC[ms][1] = __builtin_amdgcn_mfma_f32_16x16x32_bf16(a, bg1, accC[ms][1], 0, 0, 0);
            }
        }
        __builtin_amdgcn_s_setprio(0);
        // ---- epilogue C: LSE2 ----
#pragma unroll
        for (int ns = 0; ns < 2; ns++)
#pragma unroll
            for (int ms = 0; ms < 4; ms++)
#pragma unroll
                for (int r = 0; r < 4; r++) {
                    int r16 = (ms << 2) + r;
                    float u3 = accC[ms][ns][r];
                    float nm = fmaxf(Lm[2][r16], u3);
                    Ls[2][r16] = Ls[2][r16] * __expf(Lm[2][r16] - nm) + __expf(u3 - nm);
                    Lm[2][r16] = nm;
                }
    }
    // merge across the 16 col-lanes (same rows; xor of low-4 bits keeps quad)
#pragma unroll
    for (int off = 1; off <= 8; off <<= 1)
#pragma unroll
        for (int c = 0; c < 3; c++)
#pragma unroll
            for (int r16 = 0; r16 < 16; r16++) {
                float mo = __shfl_xor(Lm[c][r16], off);
                float so = __shfl_xor(Ls[c][r16], off);
                float nm = fmaxf(Lm[c][r16], mo);
                Ls[c][r16] = Ls[c][r16] * __expf(Lm[c][r16] - nm) + so * __expf(mo - nm);
                Lm[c][r16] = nm;
            }
    // block-level merge across the 8 wave column-slices (staging LDS dead now)
    __syncthreads();
    float* bm = (float*)sm;  // [3][8 w][64 rows]
    float* bs = bm + 1536;
    if (ln == 0) {
#pragma unroll
        for (int c = 0; c < 3; c++)
#pragma unroll
            for (int r16 = 0; r16 < 16; r16++) {
                int row = ((r16 >> 2) << 4) + (quad << 2) + (r16 & 3);
                bm[(c * 8 + w) * 64 + row] = Lm[c][r16];
                bs[(c * 8 + w) * 64 + row] = Ls[c][r16];
            }
    }
    __syncthreads();
    if (tid < 192) {
        int c = tid >> 6, row = tid & 63;
        float M = -1e30f, S = 0.f;
#pragma unroll
        for (int q = 0; q < 8; q++) {
            float m = bm[(c * 8 + q) * 64 + row];
            float s = bs[(c * 8 + q) * 64 + row];
            float Mn = fmaxf(M, m);
            S = S * __expf(M - Mn) + s * __expf(m - Mn);
            M = Mn;
        }
        part[(vs * 6 + c * 2) * 4096 + bt0 + row] = M;
        part[(vs * 6 + c * 2 + 1) * 4096 + bt0 + row] = S;
    }
}

// ---------------- 7) gx = z . w_gen[x] + b_gen[x] ----------------
__global__ void k_gx(const float* __restrict__ z, const int* __restrict__ x,
                     const float* __restrict__ w_gen, const float* __restrict__ b_gen,
                     float* __restrict__ gx) {
    int bt = blockIdx.x, k = threadIdx.x;
    int xi = x[bt];
    float p = z[bt * 256 + k] * w_gen[xi * 256 + k];
    __shared__ float red[256];
    red[k] = p;
    __syncthreads();
    for (int s = 128; s > 0; s >>= 1) {
        if (k < s) red[k] += red[k + s];
        __syncthreads();
    }
    if (k == 0) gx[bt] = red[0] + b_gen[xi];
}

// ---------------- 8) finalize (merge 8 V-split partials) ----------------
__device__ __forceinline__ float lse8(const float* __restrict__ part, int comp, int bt) {
    float M = -1e30f, S = 0.f;
#pragma unroll
    for (int vsi = 0; vsi < 8; vsi++) {
        float m = part[(vsi * 6 + comp) * 4096 + bt];
        float s = part[(vsi * 6 + comp + 1) * 4096 + bt];
        float Mn = fmaxf(M, m);
        S = S * __expf(M - Mn) + s * __expf(m - Mn);
        M = Mn;
    }
    return M + logf(S);
}

__global__ void k_final(const float* __restrict__ part, const float* __restrict__ qz,
                        const float* __restrict__ gxv, const int* __restrict__ x_sl,
                        float* __restrict__ out) {
    int tid = threadIdx.x;
    float S = 0.f;
    for (int bt = tid; bt < 4096; bt += 256) {
        int b = bt >> 7, t = bt & 127;
        if (t < x_sl[b]) {
            float lse1 = lse8(part, 0, bt);
            float lse2 = lse8(part, 2, bt);
            float lse3 = lse8(part, 4, bt);
            float p_z = lse2 - lse1;
            float kl = qz[bt] - p_z;
            float px = gxv[bt] - lse3;
            S += px - kl;
        }
    }
    __shared__ float red[256];
    red[tid] = S;
    __syncthreads();
    for (int s = 128; s > 0; s >>= 1) {
        if (tid < s) red[tid] += red[tid + s];
        __syncthreads();
    }
    if (tid == 0) {
        int sl = 0;
        for (int b = 0; b < 32; b++) sl += x_sl[b];
        out[0] = -(red[0] / (float)sl);
    }
}

extern "C" void kernel_launch(void* const* d_in, const int* in_sizes, int n_in,
                              void* d_out, int out_size, void* d_ws, size_t ws_size,
                              hipStream_t stream) {
    const int* x = (const int*)d_in[0];
    const int* x_sl = (const int*)d_in[1];
    const float* eps = (const float*)d_in[2];
    const float* emb = (const float*)d_in[3];
    const float* w_ih = (const float*)d_in[4];
    const float* w_hh = (const float*)d_in[5];
    const float* b_ih = (const float*)d_in[6];
    const float* b_hh = (const float*)d_in[7];
    const float* w_prior = (const float*)d_in[8];
    const float* b_prior = (const float*)d_in[9];
    const float* w_gen = (const float*)d_in[10];
    const float* b_gen = (const float*)d_in[11];

    float* ws = (float*)d_ws;
    float* z = ws;
    float* qz = ws + 1048576;
    ushort* hb = (ushort*)(ws + 1052672);            // BT*H bf16 = 4 MB
    ushort* zb = (ushort*)(ws + 1052672 + 1048576);  // BT*K bf16 = 2 MB
    float* gx = ws + 3149824;
    float* region = ws + 3252224;
    float* xp = region;
    uint4* wpIF = (uint4*)(region + 8388608);
    uint4* wpGO = wpIF + 65536;
    unsigned* hpk = (unsigned*)(region + 8912896);  // 1048576 dwords
    ushort* wb = (ushort*)(region + 9961472);       // w_ih bf16, 1 MB (phase 1)
    ushort* Pb = (ushort*)(region);                 // phase 2 (xp dead)
    ushort* Qb = (ushort*)(region + 2621440);
    ushort* Gb = (ushort*)(region + 5242880);
    float* part = region + 6553600;                 // 8*6*4096
    float* cv = region + 13107200;

    k_embed<<<4096, 256, 0, stream>>>(x, x_sl, eps, emb, z, zb, qz);
    k_pack_w<<<512, 256, 0, stream>>>(w_ih, wb, 6);  // w_ih -> bf16 (2048 rows < VV)
    k_xpm<<<512, 512, 0, stream>>>(zb, wb, b_ih, b_hh, xp);
    k_wpack2<<<dim3(256, 2), 256, 0, stream>>>(w_hh, wpIF, wpGO);
    hipMemsetAsync(hpk, 0xFF, 4194304, stream);  // sentinel: f16 NaN pairs
    {
        hipFuncSetAttribute((const void*)k_lstm, hipFuncAttributeMaxDynamicSharedMemorySize, 133248);
        void* args[] = {(void*)&xp, (void*)&wpIF, (void*)&wpGO, (void*)&hb, (void*)&hpk};
        hipLaunchCooperativeKernel((const void*)k_lstm, dim3(256), dim3(256), args, 133248, stream);
    }
    // xp/wpIF/wpGO/hpk/wb dead; overlay Pb/Qb/Gb/part/cv
    k_pack_w<<<5120, 256, 0, stream>>>(w_prior, Pb, 7);
    k_pack_w<<<2560, 256, 0, stream>>>(w_gen, Gb, 6);
    k_pack_q<<<10240, 256, 0, stream>>>(emb, Qb, cv);
    hipFuncSetAttribute((const void*)k_scores, hipFuncAttributeMaxDynamicSharedMemorySize, 131072);
    k_scores<<<512, 512, 131072, stream>>>(hb, zb, Pb, Qb, Gb, cv, b_prior, b_gen, part);
    k_gx<<<4096, 256, 0, stream>>>(z, x, w_gen, b_gen, gx);
    k_final<<<1, 256, 0, stream>>>(part, qz, gx, x_sl, (float*)d_out);
}

// Round 13
// 714.423 us; speedup vs baseline: 1.7850x; 1.0653x over previous
//
#include <hip/hip_runtime.h>
#include <hip/hip_bf16.h>
#include <math.h>

// Sizes fixed by the problem
#define BB 32
#define TT 128
#define KK 256
#define HH 512
#define VV 10000
#define VP 10240
#define BT 4096           // B*T
#define HLOG2PI 0.91893853320467274178f
#define FMSHIFT 16.0f     // fixed LSE shift for bounded-logit comps (|u| <= ~10)

// ---- workspace layout (float offsets) ----
// z       : 0          1048576   (BT*K, f32 — used by k_gx)
// qz      : 1048576    4096
// hb      : 1052672    1048576 floats worth = BT*H bf16 (ushort)
// zb      : 2101248    524288 floats worth  = BT*K bf16 (ushort)
// gx      : 3149824    4096
// region  : 3252224    13117440
//  phase 1 (lstm): xp(0..8388608) wpIF(+8388608) wpGO(+8650752)
//                  hpk(+8912896, 1048576 dwords) wb(+9961472, 524288 ushorts)
//  phase 2 (scores), overlaying dead xp: Pb / Qb / Gb / part / psum / cv

typedef short bf16x8 __attribute__((ext_vector_type(8)));
typedef float f32x4 __attribute__((ext_vector_type(4)));

__device__ __forceinline__ float softplus_b(float x) {
    float ax = fabsf(x);
    return fmaxf(x, 0.0f) + log2f(1.0f + exp2f(-ax));
}
__device__ __forceinline__ float sigm(float x) { return 1.0f / (1.0f + expf(-x)); }
// fast variants for the LSTM serial gate path (bf16-level accuracy is plenty)
__device__ __forceinline__ float fsigm(float x) { return 1.0f / (1.0f + __expf(-x)); }
__device__ __forceinline__ float ftanh(float x) {
    float e = __expf(2.0f * x);
    return 1.0f - 2.0f / (e + 1.0f);
}
__device__ __forceinline__ unsigned short f2bf(float f) {
    unsigned u = __float_as_uint(f);
    u += 0x7FFFu + ((u >> 16) & 1u);
    return (unsigned short)(u >> 16);
}
typedef _Float16 h2f16 __attribute__((ext_vector_type(2)));
__device__ __forceinline__ unsigned pkh2(float a, float b) {
    h2f16 h;
    h.x = (_Float16)a;
    h.y = (_Float16)b;
    return *(unsigned*)&h;
}
__device__ __forceinline__ float fdot2u(unsigned a, unsigned b, float c) {
    h2f16 ah = *(h2f16*)&a, bh = *(h2f16*)&b;
#if __has_builtin(__builtin_amdgcn_fdot2)
    return __builtin_amdgcn_fdot2(ah, bh, c, false);
#else
    return c + (float)ah.x * (float)bh.x + (float)ah.y * (float)bh.y;
#endif
}
// square a bf16x8 in-register: bf16->f32 is <<16; repack with v_cvt_pk_bf16_f32 (RNE)
__device__ __forceinline__ bf16x8 bsq(bf16x8 a) {
    union { bf16x8 v; unsigned w[4]; } u, r;
    u.v = a;
#pragma unroll
    for (int i = 0; i < 4; i++) {
        float lo = __uint_as_float(u.w[i] << 16);
        float hi = __uint_as_float(u.w[i] & 0xFFFF0000u);
        lo *= lo;
        hi *= hi;
        asm("v_cvt_pk_bf16_f32 %0, %1, %2" : "=v"(r.w[i]) : "v"(lo), "v"(hi));
    }
    return r.v;
}

// ---------------- 1) embedding -> z (f32 + bf16), q_z_lp ----------------
__global__ void k_embed(const int* __restrict__ x, const int* __restrict__ x_sl,
                        const float* __restrict__ eps, const float* __restrict__ emb,
                        float* __restrict__ z, ushort* __restrict__ zb,
                        float* __restrict__ qz) {
    int bt = blockIdx.x;
    int b = bt >> 7, t = bt & 127;
    int k = threadIdx.x;
    int xi = x[bt];
    float e1 = emb[xi * 512 + k];
    float sg = softplus_b(emb[xi * 512 + 256 + k]);
    float ep = eps[bt * 256 + k];
    float mk = (t < x_sl[b]) ? 1.f : 0.f;
    float zv = (e1 + sg * ep) * mk;
    z[bt * 256 + k] = zv;
    zb[bt * 256 + k] = f2bf(zv);
    float q = -HLOG2PI - logf(sg) - 0.5f * ep * ep;
    __shared__ float red[256];
    red[k] = q;
    __syncthreads();
    for (int s = 128; s > 0; s >>= 1) {
        if (k < s) red[k] += red[k + s];
        __syncthreads();
    }
    if (k == 0) qz[bt] = red[0];
}

// ---------------- 2) x_proj via MFMA: xp = z_shift @ w_ih^T + b_ih + b_hh ----------------
__global__ __launch_bounds__(512) void k_xpm(const ushort* __restrict__ zb,
                                             const ushort* __restrict__ wb,
                                             const float* __restrict__ b_ih,
                                             const float* __restrict__ b_hh,
                                             float* __restrict__ xp) {
    __shared__ ushort zs[16384];  // [kc 8][256 granules of 16B], swizzled
    int tid = threadIdx.x;
    int mb = blockIdx.x >> 3;
    int nb = blockIdx.x & 7;
    int bt0 = mb << 6;
    int n0base = nb << 8;
    // stage A: z_shift rows bt0..bt0+63 (t==0 -> zeros), bf16 16B copies
    for (int i = tid; i < 2048; i += 512) {
        int quad = i & 3, row = (i >> 2) & 63, kc = i >> 8;  // kc 0..7
        int bt = bt0 + row;
        uint4 v = make_uint4(0, 0, 0, 0);
        if ((bt & 127) != 0)
            v = *(const uint4*)(zb + (size_t)(bt - 1) * 256 + kc * 32 + quad * 8);
        int g = (((row << 2) + (quad ^ (row & 3))) ^ (((row >> 2) & 1) << 2));
        *(uint4*)(zs + kc * 2048 + g * 8) = v;
    }
    __syncthreads();
    int w = tid >> 6, l = tid & 63;
    int quad = l >> 4, ln = l & 15;
    int n0 = n0base + (w << 5);
    const bf16x8* zs8 = (const bf16x8*)zs;
    const bf16x8* wb8 = (const bf16x8*)wb;
    int g0 = (((ln << 2) + (quad ^ (ln & 3))) ^ (((ln >> 2) & 1) << 2));
    int rb = (n0 + ln) << 5;  // wb granule row base (32 granules/row; ns adds 512)
    f32x4 acc[4][2];
#pragma unroll
    for (int ns = 0; ns < 2; ns++) {
        int col = n0 + (ns << 4) + ln;
        float bias = b_ih[col] + b_hh[col];
#pragma unroll
        for (int ms = 0; ms < 4; ms++) acc[ms][ns] = bias;
    }
#pragma unroll
    for (int kc = 0; kc < 8; kc++) {
        bf16x8 b0 = wb8[rb + (kc << 2) + quad];
        bf16x8 b1 = wb8[rb + 512 + (kc << 2) + quad];
#pragma unroll
        for (int ms = 0; ms < 4; ms++) {
            bf16x8 a = zs8[(kc << 8) + g0 + (ms << 6)];
            acc[ms][0] = __builtin_amdgcn_mfma_f32_16x16x32_bf16(a, b0, acc[ms][0], 0, 0, 0);
            acc[ms][1] = __builtin_amdgcn_mfma_f32_16x16x32_bf16(a, b1, acc[ms][1], 0, 0, 0);
        }
    }
    // write: row = 16*ms + 4*quad + r, col = n0 + 16*ns + ln
#pragma unroll
    for (int ms = 0; ms < 4; ms++)
#pragma unroll
        for (int ns = 0; ns < 2; ns++)
#pragma unroll
            for (int r = 0; r < 4; r++) {
                int row = bt0 + (ms << 4) + (quad << 2) + r;
                xp[(size_t)row * 2048 + n0 + (ns << 4) + ln] = acc[ms][ns][r];
            }
}

// ---------------- 2b) pack w_hh -> f16 pairs, layouts for k_lstm v2 ----------------
__global__ __launch_bounds__(256) void k_wpack2(const float* __restrict__ w_hh,
                                                uint4* __restrict__ wpIF,
                                                uint4* __restrict__ wpGO) {
    int o = blockIdx.x * 256 + threadIdx.x;  // 0..65535
    if (blockIdx.y == 0) {
        int kq = o & 3, j_local = (o >> 2) & 63, q = (o >> 8) & 31, m = o >> 13;
        int jg = (m << 6) + j_local;
        int k = (kq << 7) + (q << 2);
        const float* wi = w_hh + (size_t)jg * 512 + k;
        const float* wf = w_hh + (size_t)(512 + jg) * 512 + k;
        uint4 u;
        u.x = pkh2(wi[0], wi[1]); u.y = pkh2(wi[2], wi[3]);
        u.z = pkh2(wf[0], wf[1]); u.w = pkh2(wf[2], wf[3]);
        wpIF[o] = u;
    } else {
        int q = o & 31, kq = (o >> 5) & 3, j_local = (o >> 7) & 63, m = o >> 13;
        int jg = (m << 6) + j_local;
        int k = (kq << 7) + (q << 2);
        const float* wg = w_hh + (size_t)(1024 + jg) * 512 + k;
        const float* wo = w_hh + (size_t)(1536 + jg) * 512 + k;
        uint4 u;
        u.x = pkh2(wg[0], wg[1]); u.y = pkh2(wg[2], wg[3]);
        u.z = pkh2(wo[0], wo[1]); u.w = pkh2(wo[2], wo[3]);
        wpGO[o] = u;
    }
}

// ---------------- 3) LSTM v5: v6 loop body + skewed LDS bases only ----------------
__global__ __launch_bounds__(256, 1) void k_lstm(const float* __restrict__ xp,
                                                 const uint4* __restrict__ wpIF,
                                                 const uint4* __restrict__ wpGO,
                                                 ushort* __restrict__ h_all,
                                                 unsigned* __restrict__ hpk) {
    extern __shared__ char smc[];
    uint4* wif = (uint4*)smc;                   // [q 32][wave-linear 256] = 128 KB
    unsigned* hs2 = (unsigned*)(smc + 131072);  // [2][272] dwords (skewed)
    int bid = blockIdx.x;
    int b = bid & 31;
    int m = bid >> 5;
    int tid = threadIdx.x;
    int w = tid >> 6, l = tid & 63;
    int jj = l >> 2, kq = l & 3;
    int j_local = (w << 4) + jj;
    int j_global = (m << 6) + j_local;
    const uint4* srcIF = wpIF + ((size_t)m << 13);
    for (int i = tid; i < 8192; i += 256) wif[i] = srcIF[i];
    uint4 wgo[32];
    const uint4* srcGO = wpGO + ((size_t)((((m << 6) + j_local) << 2) + kq) << 5);
#pragma unroll
    for (int q = 0; q < 32; q++) wgo[q] = srcGO[q];
    const uint4* wifp = wif + (w << 6) + l;
    int skslot = tid + ((tid >> 6) << 2);  // skewed write slot
    float c = 0.f;
    __syncthreads();
    for (int t = 0; t < 128; t++) {
        int bt = (b << 7) + t;
        float xg0 = 0.f, xg1 = 0.f, xg2 = 0.f, xg3 = 0.f;
        if (kq == 0) {  // prefetch xp before the poll (independent loads)
            const float* xpr = xp + (size_t)bt * 2048 + j_global;
            xg0 = xpr[0]; xg1 = xpr[512]; xg2 = xpr[1024]; xg3 = xpr[1536];
        }
        float a0 = 0.f, a1 = 0.f, a2 = 0.f, a3 = 0.f;
        if (t > 0) {
            const unsigned* src = hpk + ((size_t)(bt - 1) << 8);
            unsigned u;
            do {
                u = __hip_atomic_load(src + tid, __ATOMIC_RELAXED, __HIP_MEMORY_SCOPE_AGENT);
            } while (u == 0xFFFFFFFFu);
            unsigned* hbuf = hs2 + ((t - 1) & 1) * 272;
            hbuf[skslot] = u;
            __syncthreads();
            const unsigned* hp2 = hbuf + kq * 68;
#pragma unroll
            for (int q = 0; q < 32; q++) {
                uint4 A = wifp[q << 8];
                uint4 B = wgo[q];
                unsigned p0 = hp2[q << 1];
                unsigned p1 = hp2[(q << 1) + 1];
                a0 = fdot2u(A.x, p0, a0); a0 = fdot2u(A.y, p1, a0);
                a1 = fdot2u(A.z, p0, a1); a1 = fdot2u(A.w, p1, a1);
                a2 = fdot2u(B.x, p0, a2); a2 = fdot2u(B.y, p1, a2);
                a3 = fdot2u(B.z, p0, a3); a3 = fdot2u(B.w, p1, a3);
            }
#pragma unroll
            for (int off = 1; off <= 2; off <<= 1) {
                a0 += __shfl_xor(a0, off);
                a1 += __shfl_xor(a1, off);
                a2 += __shfl_xor(a2, off);
                a3 += __shfl_xor(a3, off);
            }
        }
        float h = 0.f;
        if (kq == 0) {
            float g0 = xg0 + a0, g1 = xg1 + a1, g2 = xg2 + a2, g3 = xg3 + a3;
            c = fsigm(g1) * c + fsigm(g0) * ftanh(g2);
            h = fsigm(g3) * ftanh(c);
            h_all[(size_t)bt * 512 + j_global] = f2bf(h);  // bf16, read post-kernel
        }
        float hp = __shfl_xor(h, 4);  // leader jj even <- h of jj+1
        if (kq == 0 && (jj & 1) == 0) {
            unsigned u = pkh2(h, hp);
            __hip_atomic_store(hpk + ((size_t)bt << 8) + (m << 5) + (w << 3) + (jj >> 1),
                               u, __ATOMIC_RELAXED, __HIP_MEMORY_SCOPE_AGENT);
        }
    }
}

// ---------------- 4a) cast weights -> bf16 row-major [v][2^kshift granules] ----------------
__global__ __launch_bounds__(256) void k_pack_w(const float* __restrict__ src,
                                                ushort* __restrict__ dst, int kshift) {
    int o = blockIdx.x * 256 + threadIdx.x;  // one ushort4 unit
    int c = o & ((1 << kshift) - 1);
    int r = o >> kshift;
    ushort4 u = make_ushort4(0, 0, 0, 0);
    if (r < VV) {
        float4 v = *(const float4*)(src + ((size_t)r << (kshift + 2)) + (c << 2));
        u = make_ushort4(f2bf(v.x), f2bf(v.y), f2bf(v.z), f2bf(v.w));
    }
    *(ushort4*)(dst + ((size_t)o << 2)) = u;
}

// ---------------- 4b) Qb rows [2*iv*mu (256) | -iv (256)] bf16 + const_v ----------------
__global__ void k_pack_q(const float* __restrict__ emb, ushort* __restrict__ Qb,
                         float* __restrict__ cv) {
    int v = blockIdx.x, k = threadIdx.x;
    if (v >= VV) {
        Qb[((size_t)v << 9) + k] = 0;
        Qb[((size_t)v << 9) + 256 + k] = 0;
        if (k == 0) cv[v] = 0.f;
        return;
    }
    float mu = emb[(size_t)v * 512 + k];
    float sg = softplus_b(emb[(size_t)v * 512 + 256 + k]);
    float iv = 0.5f / (sg * sg);
    Qb[((size_t)v << 9) + k] = f2bf(2.f * iv * mu);
    Qb[((size_t)v << 9) + 256 + k] = f2bf(-iv);
    float ct = -HLOG2PI - logf(sg) - mu * mu * iv;
    __shared__ float red[256];
    red[k] = ct;
    __syncthreads();
    for (int s = 128; s > 0; s >>= 1) {
        if (k < s) red[k] += red[k + s];
        __syncthreads();
    }
    if (k == 0) cv[v] = red[0];
}

// ---------------- 6) fused scores v7: fixed-shift LSE for bounded comps ----------------
// Comps 0 (prior logits: |u1| <= max|h|*sum|w| ~ 8) and 2 (gen logits: |u3| <=
// |z|2*|w|2 ~ 8) have bounded logits -> plain sum of exp(u - 16) (one exp, no
// fmax/rescale) with constant M=16 written to part. Only comp 1 (lp ~ -360
// scale) keeps online max tracking. Frees Lm[0]/Lm[2] (32 VGPRs) and halves
// epilogue VALU for 2/3 comps. part/k_final format unchanged (M=16 constant).
__global__ __launch_bounds__(512, 2) void k_scores(
    const ushort* __restrict__ hb, const ushort* __restrict__ zb,
    const ushort* __restrict__ Pb, const ushort* __restrict__ Qb,
    const ushort* __restrict__ Gb, const float* __restrict__ cv,
    const float* __restrict__ b_prior, const float* __restrict__ b_gen,
    float* __restrict__ part) {
    extern __shared__ ushort sm[];
    ushort* hT = sm;           // [kc 16][64 rows][32], swizzled granules = 64 KB
    ushort* fzT = sm + 32768;  // [kc 16][64 rows][32]: kc<8 z, kc>=8 z^2 = 64 KB
    int tid = threadIdx.x;
    int vs = blockIdx.x & 7;
    int mb = blockIdx.x >> 3;
    int bt0 = mb << 6;
    int vbase = vs * 1280;
    // stage h tile (64 x 512 bf16): pure 16B copies
    for (int i = tid; i < 4096; i += 512) {
        int quad = i & 3, row = (i >> 2) & 63, kc = i >> 8;
        uint4 v = *(const uint4*)(hb + (size_t)(bt0 + row) * 512 + kc * 32 + quad * 8);
        int g = (((row << 2) + (quad ^ (row & 3))) ^ (((row >> 2) & 1) << 2));
        *(uint4*)(hT + kc * 2048 + g * 8) = v;
    }
    // stage z (copy) + z^2 (bsq once per granule)
    for (int i = tid; i < 2048; i += 512) {
        int quad = i & 3, row = (i >> 2) & 63, kc = i >> 8;  // kc 0..7
        uint4 v = *(const uint4*)(zb + (size_t)(bt0 + row) * 256 + kc * 32 + quad * 8);
        int g = (((row << 2) + (quad ^ (row & 3))) ^ (((row >> 2) & 1) << 2));
        *(uint4*)(fzT + kc * 2048 + g * 8) = v;
        bf16x8 sq = bsq(*(bf16x8*)&v);
        *(uint4*)(fzT + (kc + 8) * 2048 + g * 8) = *(uint4*)&sq;
    }
    __syncthreads();
    int w = tid >> 6, l = tid & 63;
    int quad = l >> 4, ln = l & 15;
    int nq = w;  // wave: ALL 64 rows x cols nq*32..+32 per nt group
    const bf16x8* hT8 = (const bf16x8*)hT;
    const bf16x8* fz8 = (const bf16x8*)fzT;
    const bf16x8* Pb8 = (const bf16x8*)Pb;
    const bf16x8* Qb8 = (const bf16x8*)Qb;
    const bf16x8* Gb8 = (const bf16x8*)Gb;
    // ms=0 row = ln; ms adds 16 rows => granule g0 + 64*ms (swizzle-consistent)
    int g0 = (((ln << 2) + (quad ^ (ln & 3))) ^ (((ln >> 2) & 1) << 2));
    float Ls[3][16], Lm1[16];
#pragma unroll
    for (int c = 0; c < 3; c++)
#pragma unroll
        for (int r = 0; r < 16; r++) Ls[c][r] = 0.f;
#pragma unroll
    for (int r = 0; r < 16; r++) Lm1[r] = -1e30f;
#pragma unroll 1
    for (int nt = 0; nt < 5; nt++) {
        int n0 = vbase + (nt << 8) + (nq << 5);
        int rb = (n0 + ln) << 6;  // Pb/Qb granule row base (ns adds 1024)
        int rg = (n0 + ln) << 5;  // Gb granule row base (ns adds 512)
        __builtin_amdgcn_s_setprio(1);
        // ---- chain A: prior logits, h (K=512) vs Pb ----
        f32x4 accA[4][2];
#pragma unroll
        for (int ms = 0; ms < 4; ms++) { accA[ms][0] = 0.f; accA[ms][1] = 0.f; }
#pragma unroll 2
        for (int kc = 0; kc < 16; kc++) {
            bf16x8 b0 = Pb8[rb + (kc << 2) + quad];
            bf16x8 b1 = Pb8[rb + 1024 + (kc << 2) + quad];
#pragma unroll
            for (int ms = 0; ms < 4; ms++) {
                bf16x8 a = hT8[(kc << 8) + g0 + (ms << 6)];
                accA[ms][0] = __builtin_amdgcn_mfma_f32_16x16x32_bf16(a, b0, accA[ms][0], 0, 0, 0);
                accA[ms][1] = __builtin_amdgcn_mfma_f32_16x16x32_bf16(a, b1, accA[ms][1], 0, 0, 0);
            }
        }
        __builtin_amdgcn_s_setprio(0);
        // ---- epilogue A: fixed-shift sum for comp0; fold u1+cv into accB init ----
        f32x4 accB[4][2];
#pragma unroll
        for (int ns = 0; ns < 2; ns++) {
            int col = n0 + (ns << 4) + ln;
            bool ok = col < VV;
            float bpv = ok ? b_prior[col] : 0.f;
            float cvv = ok ? cv[col] : 0.f;
#pragma unroll
            for (int ms = 0; ms < 4; ms++)
#pragma unroll
                for (int r = 0; r < 4; r++) {
                    int r16 = (ms << 2) + r;
                    float u1 = ok ? accA[ms][ns][r] + bpv : -1e30f;
                    Ls[0][r16] += __expf(u1 - FMSHIFT);  // exp(-1e30)=0 for pads
                    accB[ms][ns][r] = ok ? u1 + cvv : -1e30f;  // pad Qb rows are 0
                }
        }
        __builtin_amdgcn_s_setprio(1);
        // ---- chain B: z (kc 0..7) + z^2 (kc 8..15) vs Qb ----
#pragma unroll 2
        for (int kc = 0; kc < 16; kc++) {
            bf16x8 bq0 = Qb8[rb + (kc << 2) + quad];
            bf16x8 bq1 = Qb8[rb + 1024 + (kc << 2) + quad];
#pragma unroll
            for (int ms = 0; ms < 4; ms++) {
                bf16x8 a = fz8[(kc << 8) + g0 + (ms << 6)];
                accB[ms][0] = __builtin_amdgcn_mfma_f32_16x16x32_bf16(a, bq0, accB[ms][0], 0, 0, 0);
                accB[ms][1] = __builtin_amdgcn_mfma_f32_16x16x32_bf16(a, bq1, accB[ms][1], 0, 0, 0);
            }
        }
        __builtin_amdgcn_s_setprio(0);
        // ---- epilogue B: online LSE (comp1 has unbounded-scale lp) ----
#pragma unroll
        for (int ns = 0; ns < 2; ns++)
#pragma unroll
            for (int ms = 0; ms < 4; ms++)
#pragma unroll
                for (int r = 0; r < 4; r++) {
                    int r16 = (ms << 2) + r;
                    float u2 = accB[ms][ns][r];
                    float nm = fmaxf(Lm1[r16], u2);
                    Ls[1][r16] = Ls[1][r16] * __expf(Lm1[r16] - nm) + __expf(u2 - nm);
                    Lm1[r16] = nm;
                }
        // ---- chain C: gen logits, z (K=256) vs Gb ----
        f32x4 accC[4][2];
#pragma unroll
        for (int ns = 0; ns < 2; ns++) {
            int col = n0 + (ns << 4) + ln;
            bool ok = col < VV;
            float bgv = ok ? b_gen[col] : -1e30f;  // pad Gb rows are 0
#pragma unroll
            for (int ms = 0; ms < 4; ms++) accC[ms][ns] = bgv;
        }
        __builtin_amdgcn_s_setprio(1);
#pragma unroll 2
        for (int kc = 0; kc < 8; kc++) {
            bf16x8 bg0 = Gb8[rg + (kc << 2) + quad];
            bf16x8 bg1 = Gb8[rg + 512 + (kc << 2) + quad];
#pragma unroll
            for (int ms = 0; ms < 4; ms++) {
                bf16x8 a = fz8[(kc << 8) + g0 + (ms << 6)];
                accC[ms][0] = __builtin_amdgcn_mfma_f32_16x16x32_bf16(a, bg0, accC[ms][0], 0, 0, 0);
                accC[ms][1] = __builtin_amdgcn_mfma_f32_16x16x32_bf16(a, bg1, accC[ms][1], 0, 0, 0);
            }
        }
        __builtin_amdgcn_s_setprio(0);
        // ---- epilogue C: fixed-shift sum for comp2 ----
#pragma unroll
        for (int ns = 0; ns < 2; ns++)
#pragma unroll
            for (int ms = 0; ms < 4; ms++)
#pragma unroll
                for (int r = 0; r < 4; r++)
                    Ls[2][(ms << 2) + r] += __expf(accC[ms][ns][r] - FMSHIFT);
    }
    // merge across the 16 col-lanes (same rows; xor of low-4 bits keeps quad)
#pragma unroll
    for (int off = 1; off <= 8; off <<= 1)
#pragma unroll
        for (int r16 = 0; r16 < 16; r16++) {
            Ls[0][r16] += __shfl_xor(Ls[0][r16], off);
            Ls[2][r16] += __shfl_xor(Ls[2][r16], off);
            float mo = __shfl_xor(Lm1[r16], off);
            float so = __shfl_xor(Ls[1][r16], off);
            float nm = fmaxf(Lm1[r16], mo);
            Ls[1][r16] = Ls[1][r16] * __expf(Lm1[r16] - nm) + so * __expf(mo - nm);
            Lm1[r16] = nm;
        }
    // block-level merge across the 8 wave column-slices (staging LDS is dead now)
    __syncthreads();
    float* bs = (float*)sm;   // [3][8 w][64 rows] = 1536
    float* bm = bs + 1536;    // [8 w][64 rows] = 512 (comp1 max only)
    if (ln == 0) {
#pragma unroll
        for (int r16 = 0; r16 < 16; r16++) {
            int row = ((r16 >> 2) << 4) + (quad << 2) + (r16 & 3);
#pragma unroll
            for (int c = 0; c < 3; c++) bs[(c * 8 + w) * 64 + row] = Ls[c][r16];
            bm[w * 64 + row] = Lm1[r16];
        }
    }
    __syncthreads();
    if (tid < 192) {
        int c = tid >> 6, row = tid & 63;
        float M, S;
        if (c == 1) {
            M = -1e30f; S = 0.f;
#pragma unroll
            for (int q = 0; q < 8; q++) {
                float m = bm[q * 64 + row];
                float s = bs[(8 + q) * 64 + row];
                float Mn = fmaxf(M, m);
                S = S * __expf(M - Mn) + s * __expf(m - Mn);
                M = Mn;
            }
        } else {
            M = FMSHIFT; S = 0.f;
#pragma unroll
            for (int q = 0; q < 8; q++) S += bs[(c * 8 + q) * 64 + row];
        }
        part[(vs * 6 + c * 2) * 4096 + bt0 + row] = M;
        part[(vs * 6 + c * 2 + 1) * 4096 + bt0 + row] = S;
    }
}

// ---------------- 7) gx = z . w_gen[x] + b_gen[x] ----------------
__global__ void k_gx(const float* __restrict__ z, const int* __restrict__ x,
                     const float* __restrict__ w_gen, const float* __restrict__ b_gen,
                     float* __restrict__ gx) {
    int bt = blockIdx.x, k = threadIdx.x;
    int xi = x[bt];
    float p = z[bt * 256 + k] * w_gen[xi * 256 + k];
    __shared__ float red[256];
    red[k] = p;
    __syncthreads();
    for (int s = 128; s > 0; s >>= 1) {
        if (k < s) red[k] += red[k + s];
        __syncthreads();
    }
    if (k == 0) gx[bt] = red[0] + b_gen[xi];
}

// ---------------- 8) finalize (merge 8 V-split partials), 2-stage ----------------
__device__ __forceinline__ float lse8(const float* __restrict__ part, int comp, int bt) {
    float M = -1e30f, S = 0.f;
#pragma unroll
    for (int vsi = 0; vsi < 8; vsi++) {
        float m = part[(vsi * 6 + comp) * 4096 + bt];
        float s = part[(vsi * 6 + comp + 1) * 4096 + bt];
        float Mn = fmaxf(M, m);
        S = S * __expf(M - Mn) + s * __expf(m - Mn);
        M = Mn;
    }
    return M + logf(S);
}

// stage 1: 32 blocks x 128 threads — block bid handles batch b = bid (bt = bid*128 + t)
__global__ void k_final1(const float* __restrict__ part, const float* __restrict__ qz,
                         const float* __restrict__ gxv, const int* __restrict__ x_sl,
                         float* __restrict__ psum) {
    int bid = blockIdx.x;
    int tid = threadIdx.x;
    int bt = (bid << 7) + tid;
    float S = 0.f;
    if (tid < x_sl[bid]) {
        float lse1 = lse8(part, 0, bt);
        float lse2 = lse8(part, 2, bt);
        float lse3 = lse8(part, 4, bt);
        float p_z = lse2 - lse1;
        float kl = qz[bt] - p_z;
        float px = gxv[bt] - lse3;
        S = px - kl;
    }
    __shared__ float red[128];
    red[tid] = S;
    __syncthreads();
    for (int s = 64; s > 0; s >>= 1) {
        if (tid < s) red[tid] += red[tid + s];
        __syncthreads();
    }
    if (tid == 0) psum[bid] = red[0];
}

// stage 2: 1 block x 64 threads — reduce 32 partials, divide, negate
__global__ void k_final2(const float* __restrict__ psum, const int* __restrict__ x_sl,
                         float* __restrict__ out) {
    int tid = threadIdx.x;
    float s = (tid < 32) ? psum[tid] : 0.f;
#pragma unroll
    for (int off = 32; off >= 1; off >>= 1) s += __shfl_down(s, off);
    if (tid == 0) {
        int sl = 0;
        for (int b = 0; b < 32; b++) sl += x_sl[b];
        out[0] = -(s / (float)sl);
    }
}

extern "C" void kernel_launch(void* const* d_in, const int* in_sizes, int n_in,
                              void* d_out, int out_size, void* d_ws, size_t ws_size,
                              hipStream_t stream) {
    const int* x = (const int*)d_in[0];
    const int* x_sl = (const int*)d_in[1];
    const float* eps = (const float*)d_in[2];
    const float* emb = (const float*)d_in[3];
    const float* w_ih = (const float*)d_in[4];
    const float* w_hh = (const float*)d_in[5];
    const float* b_ih = (const float*)d_in[6];
    const float* b_hh = (const float*)d_in[7];
    const float* w_prior = (const float*)d_in[8];
    const float* b_prior = (const float*)d_in[9];
    const float* w_gen = (const float*)d_in[10];
    const float* b_gen = (const float*)d_in[11];

    float* ws = (float*)d_ws;
    float* z = ws;
    float* qz = ws + 1048576;
    ushort* hb = (ushort*)(ws + 1052672);            // BT*H bf16 = 4 MB
    ushort* zb = (ushort*)(ws + 1052672 + 1048576);  // BT*K bf16 = 2 MB
    float* gx = ws + 3149824;
    float* region = ws + 3252224;
    float* xp = region;
    uint4* wpIF = (uint4*)(region + 8388608);
    uint4* wpGO = wpIF + 65536;
    unsigned* hpk = (unsigned*)(region + 8912896);  // 1048576 dwords
    ushort* wb = (ushort*)(region + 9961472);       // w_ih bf16, 1 MB (phase 1)
    ushort* Pb = (ushort*)(region);                 // phase 2 (xp dead)
    ushort* Qb = (ushort*)(region + 2621440);
    ushort* Gb = (ushort*)(region + 5242880);
    float* part = region + 6553600;                 // 8*6*4096
    float* psum = region + 6750208;                 // 32 floats
    float* cv = region + 13107200;

    k_embed<<<4096, 256, 0, stream>>>(x, x_sl, eps, emb, z, zb, qz);
    k_pack_w<<<512, 256, 0, stream>>>(w_ih, wb, 6);  // w_ih -> bf16 (2048 rows < VV)
    k_xpm<<<512, 512, 0, stream>>>(zb, wb, b_ih, b_hh, xp);
    k_wpack2<<<dim3(256, 2), 256, 0, stream>>>(w_hh, wpIF, wpGO);
    hipMemsetAsync(hpk, 0xFF, 4194304, stream);  // sentinel: f16 NaN pairs
    {
        hipFuncSetAttribute((const void*)k_lstm, hipFuncAttributeMaxDynamicSharedMemorySize, 133248);
        void* args[] = {(void*)&xp, (void*)&wpIF, (void*)&wpGO, (void*)&hb, (void*)&hpk};
        hipLaunchCooperativeKernel((const void*)k_lstm, dim3(256), dim3(256), args, 133248, stream);
    }
    // xp/wpIF/wpGO/hpk/wb dead; overlay Pb/Qb/Gb/part/psum/cv
    k_pack_w<<<5120, 256, 0, stream>>>(w_prior, Pb, 7);
    k_pack_w<<<2560, 256, 0, stream>>>(w_gen, Gb, 6);
    k_pack_q<<<10240, 256, 0, stream>>>(emb, Qb, cv);
    hipFuncSetAttribute((const void*)k_scores, hipFuncAttributeMaxDynamicSharedMemorySize, 131072);
    k_scores<<<512, 512, 131072, stream>>>(hb, zb, Pb, Qb, Gb, cv, b_prior, b_gen, part);
    k_gx<<<4096, 256, 0, stream>>>(z, x, w_gen, b_gen, gx);
    k_final1<<<32, 128, 0, stream>>>(part, qz, gx, x_sl, psum);
    k_final2<<<1, 64, 0, stream>>>(psum, x_sl, (float*)d_out);
}